// Round 4
// baseline (197.925 us; speedup 1.0000x reference)
//
#include <hip/hip_runtime.h>
#include <math.h>

static constexpr int Dd    = 128;
static constexpr int NH    = 8;
static constexpr int NE    = 256;
static constexpr int RR    = 32;
static constexpr int NTOK  = 2048;
#define EPSF 1e-6f

__device__ __forceinline__ float elu1(float v) { return v > 0.f ? v + 1.f : expf(v); }
__device__ __forceinline__ float sigm(float v) { return 1.f / (1.f + expf(-v)); }

// ===== k_zero: clear ctx/ksum accumulators (8704 floats) =====================
__global__ __launch_bounds__(512) void k_zero(float* __restrict__ ctx,
                                              float* __restrict__ ksum) {
  int idx = blockIdx.x * 512 + threadIdx.x;       // grid 17 -> idx < 8704
  if (idx < 8192) ctx[idx] = 0.f;
  else if (idx < 8704) ksum[idx - 8192] = 0.f;
}

// ===== k_stage1: rmsnorm1 + q + kd + ku + ctx/ksum atomics (+oR/bR fold) ====
// One block per 4 tokens. k/v never leave LDS; ctx accumulated via atomics.
__global__ __launch_bounds__(512) void k_stage1(
    const float* __restrict__ x, const float* __restrict__ g1,
    const float* __restrict__ qW, const float* __restrict__ qb,
    const float* __restrict__ kdW, const float* __restrict__ kdb,
    const float* __restrict__ kuW, const float* __restrict__ kub,
    const float* __restrict__ oW, const float* __restrict__ ob,
    const float* __restrict__ rot,
    float* __restrict__ qbuf, float* __restrict__ ctx, float* __restrict__ ksum,
    float* __restrict__ oR, float* __restrict__ bR) {
  const int tid = threadIdx.x;
  const int bid = blockIdx.x;
  const int j = tid & 127, g = tid >> 7;
  const int lane = tid & 63;
  const int n0 = bid * 4;
  const int b = bid >> 7;                       // batch index

  __shared__ float4 h1T[128];
  __shared__ float4 part[3][128];
  __shared__ float4 kpart[8][32];
  __shared__ float4 kdT[32];
  __shared__ float4 kupart[256];
  __shared__ float4 rtmp[2];
  __shared__ __align__(16) float kS[8][16][4];  // k[h][d][tok], elu'd
  __shared__ __align__(16) float vS[8][16][4];  // v[h][e][tok]

  // rmsnorm1
  float xv[4];
  if (tid < 128) {
    float v[4];
#pragma unroll
    for (int t = 0; t < 4; t++) { xv[t] = x[(n0 + t) * Dd + j]; v[t] = xv[t] * xv[t]; }
#pragma unroll
    for (int o = 32; o > 0; o >>= 1) {
#pragma unroll
      for (int t = 0; t < 4; t++) v[t] += __shfl_xor(v[t], o, 64);
    }
    if (lane == 0) rtmp[tid >> 6] = make_float4(v[0], v[1], v[2], v[3]);
  }
  __syncthreads();
  if (tid < 128) {
    float g1j = g1[j];
#pragma unroll
    for (int t = 0; t < 4; t++) {
      float ss = ((const float*)&rtmp[0])[t] + ((const float*)&rtmp[1])[t];
      ((float*)&h1T[j])[t] = g1j * xv[t] * rsqrtf(ss * (1.f / 128.f) + EPSF);
    }
  }
  __syncthreads();

  // q GEMV (K-split-4) -> qbuf (elu applied)
  {
    float a0 = 0, a1 = 0, a2 = 0, a3 = 0;
    const float* Wp = qW + (g * 32) * Dd + j;
#pragma unroll 16
    for (int i = 0; i < 32; i++) {
      float4 h4 = h1T[g * 32 + i];
      float w = Wp[i * Dd];
      a0 += h4.x * w; a1 += h4.y * w; a2 += h4.z * w; a3 += h4.w * w;
    }
    if (g) part[g - 1][j] = make_float4(a0, a1, a2, a3);
    __syncthreads();
    if (g == 0) {
      float4 p0 = part[0][j], p1 = part[1][j], p2 = part[2][j];
      float bb = qb[j];
      qbuf[(n0 + 0) * Dd + j] = elu1(a0 + p0.x + p1.x + p2.x + bb);
      qbuf[(n0 + 1) * Dd + j] = elu1(a1 + p0.y + p1.y + p2.y + bb);
      qbuf[(n0 + 2) * Dd + j] = elu1(a2 + p0.z + p1.z + p2.z + bb);
      qbuf[(n0 + 3) * Dd + j] = elu1(a3 + p0.w + p1.w + p2.w + bb);
    }
    __syncthreads();
  }

  // kd GEMV: 32 cols x 8 K-splits
  if (tid < 256) {
    int col = tid & 31, ksp = tid >> 5;
    float a0 = 0, a1 = 0, a2 = 0, a3 = 0;
    const float* Wp = kdW + (ksp * 16) * RR + col;
#pragma unroll
    for (int i = 0; i < 16; i++) {
      float4 h4 = h1T[ksp * 16 + i];
      float w = Wp[i * RR];
      a0 += h4.x * w; a1 += h4.y * w; a2 += h4.z * w; a3 += h4.w * w;
    }
    kpart[ksp][col] = make_float4(a0, a1, a2, a3);
  }
  __syncthreads();
  if (tid < 32) {
    float bb = kdb[tid];
    float s0 = bb, s1 = bb, s2 = bb, s3 = bb;
#pragma unroll
    for (int k = 0; k < 8; k++) {
      float4 p = kpart[k][tid];
      s0 += p.x; s1 += p.y; s2 += p.z; s3 += p.w;
    }
    kdT[tid] = make_float4(s0, s1, s2, s3);
  }
  __syncthreads();

  // ku GEMV: 256 cols, K=32 split 2 -> kS/vS (LDS only)
  {
    int col = tid & 255, kh = tid >> 8;
    float a0 = 0, a1 = 0, a2 = 0, a3 = 0;
    const float* Wp = kuW + (kh * 16) * 256 + col;
#pragma unroll
    for (int r = 0; r < 16; r++) {
      float4 k4 = kdT[kh * 16 + r];
      float w = Wp[r * 256];
      a0 += k4.x * w; a1 += k4.y * w; a2 += k4.z * w; a3 += k4.w * w;
    }
    if (kh) kupart[col] = make_float4(a0, a1, a2, a3);
    __syncthreads();
    if (!kh) {
      float4 p = kupart[col];
      float bb = kub[col];
      float v0 = a0 + p.x + bb, v1 = a1 + p.y + bb, v2 = a2 + p.z + bb, v3 = a3 + p.w + bb;
      int h = col >> 5, off = col & 31;
      if (off < 16) {
        kS[h][off][0] = elu1(v0); kS[h][off][1] = elu1(v1);
        kS[h][off][2] = elu1(v2); kS[h][off][3] = elu1(v3);
      } else {
        vS[h][off - 16][0] = v0; vS[h][off - 16][1] = v1;
        vS[h][off - 16][2] = v2; vS[h][off - 16][3] = v3;
      }
    }
  }
  __syncthreads();

  // ctx/ksum accumulation (block-local k/v -> global atomics)
  {
    const int h = tid >> 6;            // one head per wave
    const int d = (tid >> 2) & 15;
    const int e0 = (tid & 3) * 4;
    const int bh = b * NH + h;
    float4 k4 = *(const float4*)&kS[h][d][0];
    float* cp = ctx + bh * 256 + d * 16 + e0;
#pragma unroll
    for (int ee = 0; ee < 4; ee++) {
      float4 v4 = *(const float4*)&vS[h][e0 + ee][0];
      atomicAdd(cp + ee, k4.x * v4.x + k4.y * v4.y + k4.z * v4.z + k4.w * v4.w);
    }
    if ((tid & 3) == 0)
      atomicAdd(&ksum[bh * 16 + d], k4.x + k4.y + k4.z + k4.w);
  }

  // folded: oR = oW@rot (blocks 0..31), bR = ob@rot (block 32)
  if (bid < 32) {
    int idx = bid * 512 + tid;
    int row = idx >> 7, col = idx & 127;
    const float* ow = oW + row * 128;
    float acc = 0.f;
#pragma unroll 8
    for (int k = 0; k < 128; k++) acc += ow[k] * rot[k * 128 + col];
    oR[idx] = acc;
  } else if (bid == 32 && tid < 128) {
    float acc = 0.f;
#pragma unroll 8
    for (int k = 0; k < 128; k++) acc += ob[k] * rot[k * 128 + tid];
    bR[tid] = acc;
  }
}

// ===== k_stage2: attn -> quant -> s1s2 -> rms2||gate -> top2 ->
//                 token-major experts (in-block) -> swiglu -> out+consensus ==
__global__ __launch_bounds__(512) void k_stage2(
    const float* __restrict__ x, const float* __restrict__ qbuf,
    const float* __restrict__ ctx, const float* __restrict__ ksum,
    const float* __restrict__ oR, const float* __restrict__ bR,
    const float* __restrict__ tqs,
    const float* __restrict__ s1W, const float* __restrict__ s1b,
    const float* __restrict__ s2W, const float* __restrict__ s2b,
    const float* __restrict__ g2, const float* __restrict__ gateW,
    const float* __restrict__ gateb, const float* __restrict__ expW,
    const float* __restrict__ m1W, const float* __restrict__ m1b,
    const float* __restrict__ m2W, const float* __restrict__ m2b,
    float* __restrict__ out) {
  const int tid = threadIdx.x;
  const int j = tid & 127, g = tid >> 7;
  const int lane = tid & 63;
  const int n0 = blockIdx.x * 4;
  const int b = n0 >> 9;

  __shared__ float4 bufA[128], bufB[128];
  __shared__ float4 part[3][128];
  __shared__ float4 gpart[256];
  __shared__ float4 rtmp[2];
  __shared__ float wvS[4][4]; __shared__ int wiS[4][4];
  __shared__ float zS[4][4];
  __shared__ float sWt[4][2]; __shared__ int sE[4][2];
  __shared__ float h2T[128][4];                  // h2[i][tok]
  __shared__ float epS[8][4][128];               // expert partials [pair][ksplit][col]
  __shared__ float yT[8][128];                   // expert outputs  [pair][col]
  __shared__ float4 inT[128], sT[128];

  float xres[4];
  if (tid < 128) {
#pragma unroll
    for (int t = 0; t < 4; t++) xres[t] = x[(n0 + t) * Dd + j];
  }

  // load q token-transposed
  ((float*)&bufA[j])[g] = qbuf[(n0 + g) * Dd + j];
  __syncthreads();

  // attention apply -> bufB (tid<128, K=16)
  if (tid < 128) {
    int h = j >> 4, e = j & 15;
    const float* cpt = ctx + (b * NH + h) * 256;
    const float* kpt = ksum + (b * NH + h) * 16;
    float num[4] = {0, 0, 0, 0}, den[4] = {0, 0, 0, 0};
#pragma unroll
    for (int d = 0; d < 16; d++) {
      float cx = cpt[d * 16 + e], ks = kpt[d];
      float4 q4 = bufA[h * 16 + d];
      num[0] += q4.x * cx; num[1] += q4.y * cx; num[2] += q4.z * cx; num[3] += q4.w * cx;
      den[0] += q4.x * ks; den[1] += q4.y * ks; den[2] += q4.z * ks; den[3] += q4.w * ks;
    }
#pragma unroll
    for (int t = 0; t < 4; t++) ((float*)&bufB[j])[t] = num[t] / (den[t] + EPSF);
  }
  __syncthreads();

  // z = bufB @ oR + bR; quant -> bufA
  {
    float a0 = 0, a1 = 0, a2 = 0, a3 = 0;
    const float* Wp = oR + (g * 32) * Dd + j;
#pragma unroll 16
    for (int i = 0; i < 32; i++) {
      float4 h4 = bufB[g * 32 + i];
      float w = Wp[i * Dd];
      a0 += h4.x * w; a1 += h4.y * w; a2 += h4.z * w; a3 += h4.w * w;
    }
    if (g) part[g - 1][j] = make_float4(a0, a1, a2, a3);
    __syncthreads();
    float tot[4];
    if (g == 0) {
      float4 p0 = part[0][j], p1 = part[1][j], p2 = part[2][j];
      float bb = bR[j];
      tot[0] = a0 + p0.x + p1.x + p2.x + bb; tot[1] = a1 + p0.y + p1.y + p2.y + bb;
      tot[2] = a2 + p0.z + p1.z + p2.z + bb; tot[3] = a3 + p0.w + p1.w + p2.w + bb;
      float v[4];
#pragma unroll
      for (int t = 0; t < 4; t++) v[t] = tot[t] * tot[t];
#pragma unroll
      for (int o = 32; o > 0; o >>= 1) {
#pragma unroll
        for (int t = 0; t < 4; t++) v[t] += __shfl_xor(v[t], o, 64);
      }
      if (lane == 0) rtmp[tid >> 6] = make_float4(v[0], v[1], v[2], v[3]);
    }
    __syncthreads();
    if (g == 0) {
      float scj = tqs[j];
#pragma unroll
      for (int t = 0; t < 4; t++) {
        float ss = ((const float*)&rtmp[0])[t] + ((const float*)&rtmp[1])[t];
        float mag = sqrtf(ss * (1.f / 128.f) + EPSF);
        float zc = fminf(fmaxf(tot[t], -mag), mag);
        ((float*)&bufA[j])[t] = zc * scj;
      }
    }
    __syncthreads();
  }

  // s1/s2 dual GEMV -> xn regs (+res); bufB = g2*xn; rtmp=sumsq
  float xn[4] = {0.f, 0.f, 0.f, 0.f};
  {
    float a0 = 0, a1 = 0, a2 = 0, a3 = 0;
    const float* Wp = (g < 2 ? s1W : s2W) + ((g & 1) * 64) * Dd + j;
#pragma unroll 16
    for (int i = 0; i < 64; i++) {
      float4 h4 = bufA[(g & 1) * 64 + i];
      float w = Wp[i * Dd];
      a0 += h4.x * w; a1 += h4.y * w; a2 += h4.z * w; a3 += h4.w * w;
    }
    if (g) part[g - 1][j] = make_float4(a0, a1, a2, a3);
    __syncthreads();
    if (g == 0) {
      float b1 = s1b[j], b2 = s2b[j];
      float4 p0 = part[0][j], p1 = part[1][j], p2 = part[2][j];
      float gv[4], uv[4], v[4];
      gv[0] = a0 + p0.x + b1; gv[1] = a1 + p0.y + b1;
      gv[2] = a2 + p0.z + b1; gv[3] = a3 + p0.w + b1;
      uv[0] = p1.x + p2.x + b2; uv[1] = p1.y + p2.y + b2;
      uv[2] = p1.z + p2.z + b2; uv[3] = p1.w + p2.w + b2;
      float g2j = g2[j];
#pragma unroll
      for (int t = 0; t < 4; t++) {
        xn[t] = xres[t] + gv[t] * sigm(gv[t]) * uv[t];
        ((float*)&bufB[j])[t] = g2j * xn[t];
        v[t] = xn[t] * xn[t];
      }
#pragma unroll
      for (int o = 32; o > 0; o >>= 1) {
#pragma unroll
        for (int t = 0; t < 4; t++) v[t] += __shfl_xor(v[t], o, 64);
      }
      if (lane == 0) rtmp[tid >> 6] = make_float4(v[0], v[1], v[2], v[3]);
    }
    __syncthreads();
  }

  // gate logits (K-split-2); r2 at epilogue; h2 -> LDS (h2T)
  float val[4]; float r2v[4];
  {
    int col = tid & 255, kh = tid >> 8;
    float a0 = 0, a1 = 0, a2 = 0, a3 = 0;
    const float* Wp = gateW + (kh * 64) * NE + col;
#pragma unroll 16
    for (int i = 0; i < 64; i++) {
      float4 h4 = bufB[kh * 64 + i];
      float w = Wp[i * NE];
      a0 += h4.x * w; a1 += h4.y * w; a2 += h4.z * w; a3 += h4.w * w;
    }
    if (kh) gpart[col] = make_float4(a0, a1, a2, a3);
    __syncthreads();
#pragma unroll
    for (int t = 0; t < 4; t++) {
      float ss = ((const float*)&rtmp[0])[t] + ((const float*)&rtmp[1])[t];
      r2v[t] = rsqrtf(ss * (1.f / 128.f) + EPSF);
    }
    if (!kh) {
      float4 p = gpart[col];
      float bb = gateb[col];
      val[0] = (a0 + p.x) * r2v[0] + bb; val[1] = (a1 + p.y) * r2v[1] + bb;
      val[2] = (a2 + p.z) * r2v[2] + bb; val[3] = (a3 + p.w) * r2v[3] + bb;
    }
    if (tid < 128) {
#pragma unroll
      for (int t = 0; t < 4; t++)
        h2T[j][t] = ((const float*)&bufB[j])[t] * r2v[t];
    }
  }
  __syncthreads();

  // top-2 over 256 logits (tid<256) — verified code
  float m1[4]; int i1[4];
  {
    if (tid < 256) {
      float bv[4]; int bi[4];
#pragma unroll
      for (int t = 0; t < 4; t++) { bv[t] = val[t]; bi[t] = tid; }
#pragma unroll
      for (int o = 32; o > 0; o >>= 1) {
#pragma unroll
        for (int t = 0; t < 4; t++) {
          float wv = __shfl_xor(bv[t], o, 64);
          int wi = __shfl_xor(bi[t], o, 64);
          if (wv > bv[t] || (wv == bv[t] && wi < bi[t])) { bv[t] = wv; bi[t] = wi; }
        }
      }
      if (lane == 0) {
#pragma unroll
        for (int t = 0; t < 4; t++) { wvS[tid >> 6][t] = bv[t]; wiS[tid >> 6][t] = bi[t]; }
      }
    }
    __syncthreads();
    if (tid < 256) {
#pragma unroll
      for (int t = 0; t < 4; t++) {
        m1[t] = wvS[0][t]; i1[t] = wiS[0][t];
#pragma unroll
        for (int w = 1; w < 4; w++) {
          float cv = wvS[w][t]; int ci = wiS[w][t];
          if (cv > m1[t] || (cv == m1[t] && ci < i1[t])) { m1[t] = cv; i1[t] = ci; }
        }
      }
    }
    __syncthreads();
  }
  float m2[4]; int i2[4];
  {
    if (tid < 256) {
      float bv[4]; int bi[4];
#pragma unroll
      for (int t = 0; t < 4; t++) {
        bv[t] = (tid == i1[t]) ? -INFINITY : val[t];
        bi[t] = tid;
      }
#pragma unroll
      for (int o = 32; o > 0; o >>= 1) {
#pragma unroll
        for (int t = 0; t < 4; t++) {
          float wv = __shfl_xor(bv[t], o, 64);
          int wi = __shfl_xor(bi[t], o, 64);
          if (wv > bv[t] || (wv == bv[t] && wi < bi[t])) { bv[t] = wv; bi[t] = wi; }
        }
      }
      if (lane == 0) {
#pragma unroll
        for (int t = 0; t < 4; t++) { wvS[tid >> 6][t] = bv[t]; wiS[tid >> 6][t] = bi[t]; }
      }
    }
    __syncthreads();
    if (tid < 256) {
#pragma unroll
      for (int t = 0; t < 4; t++) {
        m2[t] = wvS[0][t]; i2[t] = wiS[0][t];
#pragma unroll
        for (int w = 1; w < 4; w++) {
          float cv = wvS[w][t]; int ci = wiS[w][t];
          if (cv > m2[t] || (cv == m2[t] && ci < i2[t])) { m2[t] = cv; i2[t] = ci; }
        }
      }
    }
    __syncthreads();
  }
  {
    if (tid < 256) {
      float v[4];
#pragma unroll
      for (int t = 0; t < 4; t++) v[t] = expf(val[t] - m1[t]);
#pragma unroll
      for (int o = 32; o > 0; o >>= 1) {
#pragma unroll
        for (int t = 0; t < 4; t++) v[t] += __shfl_xor(v[t], o, 64);
      }
      if (lane == 0) {
#pragma unroll
        for (int t = 0; t < 4; t++) zS[tid >> 6][t] = v[t];
      }
    }
    __syncthreads();
  }
  if (tid < 4) {
    int t = tid;
    float Z = zS[0][t] + zS[1][t] + zS[2][t] + zS[3][t];
    float p1 = 1.f / Z;
    float p2 = expf(m2[t] - m1[t]) / Z;
    float s = p1 + p2 + EPSF;
    sE[t][0] = i1[t]; sE[t][1] = i2[t];
    sWt[t][0] = p1 / s; sWt[t][1] = p2 / s;
  }
  __syncthreads();

  // token-major experts: 8 (token,slot) GEMVs, K-split-4, 8 load streams
  {
    const float* wb[8];
#pragma unroll
    for (int p = 0; p < 8; p++) {
      int e = sE[p >> 1][p & 1];
      wb[p] = expW + (size_t)e * (Dd * Dd) + (g * 32) * Dd + j;
    }
    float acc[8] = {0, 0, 0, 0, 0, 0, 0, 0};
#pragma unroll 4
    for (int i = 0; i < 32; i++) {
      float hv[4];
#pragma unroll
      for (int t = 0; t < 4; t++) hv[t] = h2T[g * 32 + i][t];
#pragma unroll
      for (int p = 0; p < 8; p++) acc[p] += wb[p][i * Dd] * hv[p >> 1];
    }
#pragma unroll
    for (int p = 0; p < 8; p++) epS[p][g][j] = acc[p];
  }
  __syncthreads();
  {
#pragma unroll
    for (int r = 0; r < 2; r++) {
      int p = r * 4 + g;
      yT[p][j] = epS[p][0][j] + epS[p][1][j] + epS[p][2][j] + epS[p][3][j];
    }
  }
  __syncthreads();

  // weighted avg -> inT, then m1/m2 swiglu -> out; consensus from yT
  {
    float y1 = yT[g * 2 + 0][j];
    float y2 = yT[g * 2 + 1][j];
    ((float*)&inT[j])[g] = sWt[g][0] * y1 + sWt[g][1] * y2;
  }
  __syncthreads();

  {
    float a0 = 0, a1 = 0, a2 = 0, a3 = 0;
    const float* Wp = (g < 2 ? m1W : m2W) + ((g & 1) * 64) * Dd + j;
#pragma unroll 16
    for (int i = 0; i < 64; i++) {
      float4 h4 = inT[(g & 1) * 64 + i];
      float w = Wp[i * Dd];
      a0 += h4.x * w; a1 += h4.y * w; a2 += h4.z * w; a3 += h4.w * w;
    }
    if (g) part[g - 1][j] = make_float4(a0, a1, a2, a3);
    __syncthreads();
    if (g == 0) {
      float b1 = m1b[j], b2 = m2b[j];
      float4 p0 = part[0][j], p1 = part[1][j], p2 = part[2][j];
      float gv[4], uv[4];
      gv[0] = a0 + p0.x + b1; gv[1] = a1 + p0.y + b1;
      gv[2] = a2 + p0.z + b1; gv[3] = a3 + p0.w + b1;
      uv[0] = p1.x + p2.x + b2; uv[1] = p1.y + p2.y + b2;
      uv[2] = p1.z + p2.z + b2; uv[3] = p1.w + p2.w + b2;
#pragma unroll
      for (int t = 0; t < 4; t++) {
        float sv = gv[t] * sigm(gv[t]) * uv[t];
        ((float*)&sT[j])[t] = sv;
        out[(n0 + t) * Dd + j] = xn[t] + sv;   // xn from regs
      }
    }
    __syncthreads();
  }

  if (tid < 128) {
    float v[4];
#pragma unroll
    for (int t = 0; t < 4; t++) {
      float sv = ((const float*)&sT[j])[t];
      float d1 = yT[t * 2 + 0][j] - sv;
      float d2 = yT[t * 2 + 1][j] - sv;
      v[t] = sWt[t][0] * d1 * d1 + sWt[t][1] * d2 * d2;
    }
#pragma unroll
    for (int o = 32; o > 0; o >>= 1) {
#pragma unroll
      for (int t = 0; t < 4; t++) v[t] += __shfl_xor(v[t], o, 64);
    }
    if (lane == 0) rtmp[tid >> 6] = make_float4(v[0], v[1], v[2], v[3]);
  }
  __syncthreads();
  if (tid < 4) {
    float s = ((const float*)&rtmp[0])[tid] + ((const float*)&rtmp[1])[tid];
    out[NTOK * Dd + n0 + tid] = expf(-s * (1.f / 128.f));
  }
}

// ============================================================================
extern "C" void kernel_launch(void* const* d_in, const int* in_sizes, int n_in,
                              void* d_out, int out_size, void* d_ws, size_t ws_size,
                              hipStream_t stream) {
  const float* x   = (const float*)d_in[0];
  const float* g1  = (const float*)d_in[1];
  const float* qW  = (const float*)d_in[2];
  const float* qb  = (const float*)d_in[3];
  const float* kdW = (const float*)d_in[4];
  const float* kdb = (const float*)d_in[5];
  const float* kuW = (const float*)d_in[6];
  const float* kub = (const float*)d_in[7];
  const float* oW  = (const float*)d_in[8];
  const float* ob  = (const float*)d_in[9];
  const float* rot = (const float*)d_in[10];
  const float* tqs = (const float*)d_in[11];
  const float* s1W = (const float*)d_in[12];
  const float* s1b = (const float*)d_in[13];
  const float* s2W = (const float*)d_in[14];
  const float* s2b = (const float*)d_in[15];
  const float* g2  = (const float*)d_in[16];
  const float* gW  = (const float*)d_in[17];
  const float* gb  = (const float*)d_in[18];
  const float* eW  = (const float*)d_in[19];
  const float* m1W = (const float*)d_in[20];
  const float* m1b = (const float*)d_in[21];
  const float* m2W = (const float*)d_in[22];
  const float* m2b = (const float*)d_in[23];
  float* out = (float*)d_out;
  float* ws  = (float*)d_ws;

  float* ctx  = ws;              // 8192
  float* ksum = ws + 8192;       // 512
  float* oR   = ws + 8704;       // 16384
  float* bR   = ws + 25088;      // 128
  float* qbuf = ws + 25216;      // 262144

  k_zero<<<17, 512, 0, stream>>>(ctx, ksum);
  k_stage1<<<NTOK / 4, 512, 0, stream>>>(x, g1, qW, qb, kdW, kdb, kuW, kub,
                                         oW, ob, rot, qbuf, ctx, ksum, oR, bR);
  k_stage2<<<NTOK / 4, 512, 0, stream>>>(x, qbuf, ctx, ksum, oR, bR, tqs,
                                         s1W, s1b, s2W, s2b, g2, gW, gb, eW,
                                         m1W, m1b, m2W, m2b, out);
}

// Round 5
// 184.821 us; speedup vs baseline: 1.0709x; 1.0709x over previous
//
#include <hip/hip_runtime.h>
#include <math.h>

static constexpr int Dd    = 128;
static constexpr int NH    = 8;
static constexpr int NE    = 256;
static constexpr int RR    = 32;
static constexpr int NTOK  = 2048;
static constexpr int SLOTS = 256;
static constexpr int NCPY  = 16;     // ctx accumulator stripes (8-way contention)
#define EPSF 1e-6f

__device__ __forceinline__ float elu1(float v) { return v > 0.f ? v + 1.f : expf(v); }
__device__ __forceinline__ float sigm(float v) { return 1.f / (1.f + expf(-v)); }

// ===== k_zero: clear striped ctx/ksum accumulators + cnt =====================
__global__ __launch_bounds__(512) void k_zero(float* __restrict__ ctxp,
                                              float* __restrict__ ksump,
                                              int* __restrict__ cnt) {
  int idx = blockIdx.x * 512 + threadIdx.x;          // grid 273 -> idx < 139776
  if (idx < NCPY * 8192) ctxp[idx] = 0.f;
  else if (idx < NCPY * 8192 + NCPY * 512) ksump[idx - NCPY * 8192] = 0.f;
  else if (idx < NCPY * 8192 + NCPY * 512 + NE) cnt[idx - NCPY * 8192 - NCPY * 512] = 0;
}

// ===== k_pre: rmsnorm1 + q + kd + ku + striped ctx/ksum atomics (+oR fold) ==
__global__ __launch_bounds__(512) void k_pre(
    const float* __restrict__ x, const float* __restrict__ g1,
    const float* __restrict__ qW, const float* __restrict__ qb,
    const float* __restrict__ kdW, const float* __restrict__ kdb,
    const float* __restrict__ kuW, const float* __restrict__ kub,
    const float* __restrict__ oW, const float* __restrict__ ob,
    const float* __restrict__ rot,
    float* __restrict__ qbuf, float* __restrict__ ctxp, float* __restrict__ ksump,
    float* __restrict__ oR, float* __restrict__ bR) {
  const int tid = threadIdx.x;
  const int bid = blockIdx.x;
  const int j = tid & 127, g = tid >> 7;
  const int lane = tid & 63;
  const int n0 = bid * 4;
  const int b = bid >> 7;                       // batch index

  __shared__ float4 h1T[128];
  __shared__ float4 part[3][128];
  __shared__ float4 kpart[8][32];
  __shared__ float4 kdT[32];
  __shared__ float4 kupart[256];
  __shared__ float4 rtmp[2];
  __shared__ __align__(16) float kS[8][16][4];  // k[h][d][tok], elu'd
  __shared__ __align__(16) float vS[8][16][4];  // v[h][e][tok]

  // rmsnorm1
  float xv[4];
  if (tid < 128) {
    float v[4];
#pragma unroll
    for (int t = 0; t < 4; t++) { xv[t] = x[(n0 + t) * Dd + j]; v[t] = xv[t] * xv[t]; }
#pragma unroll
    for (int o = 32; o > 0; o >>= 1) {
#pragma unroll
      for (int t = 0; t < 4; t++) v[t] += __shfl_xor(v[t], o, 64);
    }
    if (lane == 0) rtmp[tid >> 6] = make_float4(v[0], v[1], v[2], v[3]);
  }
  __syncthreads();
  if (tid < 128) {
    float g1j = g1[j];
#pragma unroll
    for (int t = 0; t < 4; t++) {
      float ss = ((const float*)&rtmp[0])[t] + ((const float*)&rtmp[1])[t];
      ((float*)&h1T[j])[t] = g1j * xv[t] * rsqrtf(ss * (1.f / 128.f) + EPSF);
    }
  }
  __syncthreads();

  // q GEMV (K-split-4) -> qbuf (elu applied)
  {
    float a0 = 0, a1 = 0, a2 = 0, a3 = 0;
    const float* Wp = qW + (g * 32) * Dd + j;
#pragma unroll 16
    for (int i = 0; i < 32; i++) {
      float4 h4 = h1T[g * 32 + i];
      float w = Wp[i * Dd];
      a0 += h4.x * w; a1 += h4.y * w; a2 += h4.z * w; a3 += h4.w * w;
    }
    if (g) part[g - 1][j] = make_float4(a0, a1, a2, a3);
    __syncthreads();
    if (g == 0) {
      float4 p0 = part[0][j], p1 = part[1][j], p2 = part[2][j];
      float bb = qb[j];
      qbuf[(n0 + 0) * Dd + j] = elu1(a0 + p0.x + p1.x + p2.x + bb);
      qbuf[(n0 + 1) * Dd + j] = elu1(a1 + p0.y + p1.y + p2.y + bb);
      qbuf[(n0 + 2) * Dd + j] = elu1(a2 + p0.z + p1.z + p2.z + bb);
      qbuf[(n0 + 3) * Dd + j] = elu1(a3 + p0.w + p1.w + p2.w + bb);
    }
    __syncthreads();
  }

  // kd GEMV: 32 cols x 8 K-splits
  if (tid < 256) {
    int col = tid & 31, ksp = tid >> 5;
    float a0 = 0, a1 = 0, a2 = 0, a3 = 0;
    const float* Wp = kdW + (ksp * 16) * RR + col;
#pragma unroll
    for (int i = 0; i < 16; i++) {
      float4 h4 = h1T[ksp * 16 + i];
      float w = Wp[i * RR];
      a0 += h4.x * w; a1 += h4.y * w; a2 += h4.z * w; a3 += h4.w * w;
    }
    kpart[ksp][col] = make_float4(a0, a1, a2, a3);
  }
  __syncthreads();
  if (tid < 32) {
    float bb = kdb[tid];
    float s0 = bb, s1 = bb, s2 = bb, s3 = bb;
#pragma unroll
    for (int k = 0; k < 8; k++) {
      float4 p = kpart[k][tid];
      s0 += p.x; s1 += p.y; s2 += p.z; s3 += p.w;
    }
    kdT[tid] = make_float4(s0, s1, s2, s3);
  }
  __syncthreads();

  // ku GEMV: 256 cols, K=32 split 2 -> kS/vS (LDS only)
  {
    int col = tid & 255, kh = tid >> 8;
    float a0 = 0, a1 = 0, a2 = 0, a3 = 0;
    const float* Wp = kuW + (kh * 16) * 256 + col;
#pragma unroll
    for (int r = 0; r < 16; r++) {
      float4 k4 = kdT[kh * 16 + r];
      float w = Wp[r * 256];
      a0 += k4.x * w; a1 += k4.y * w; a2 += k4.z * w; a3 += k4.w * w;
    }
    if (kh) kupart[col] = make_float4(a0, a1, a2, a3);
    __syncthreads();
    if (!kh) {
      float4 p = kupart[col];
      float bb = kub[col];
      float v0 = a0 + p.x + bb, v1 = a1 + p.y + bb, v2 = a2 + p.z + bb, v3 = a3 + p.w + bb;
      int h = col >> 5, off = col & 31;
      if (off < 16) {
        kS[h][off][0] = elu1(v0); kS[h][off][1] = elu1(v1);
        kS[h][off][2] = elu1(v2); kS[h][off][3] = elu1(v3);
      } else {
        vS[h][off - 16][0] = v0; vS[h][off - 16][1] = v1;
        vS[h][off - 16][2] = v2; vS[h][off - 16][3] = v3;
      }
    }
  }
  __syncthreads();

  // ctx/ksum accumulation into stripe (bid & 15): 8-way per-address contention
  {
    const int h = tid >> 6;            // one head per wave
    const int d = (tid >> 2) & 15;
    const int e0 = (tid & 3) * 4;
    const int bh = b * NH + h;
    const int cpy = bid & (NCPY - 1);
    float4 k4 = *(const float4*)&kS[h][d][0];
    float* cp = ctxp + (cpy * 32 + bh) * 256 + d * 16 + e0;
#pragma unroll
    for (int ee = 0; ee < 4; ee++) {
      float4 v4 = *(const float4*)&vS[h][e0 + ee][0];
      atomicAdd(cp + ee, k4.x * v4.x + k4.y * v4.y + k4.z * v4.z + k4.w * v4.w);
    }
    if ((tid & 3) == 0)
      atomicAdd(&ksump[(cpy * 32 + bh) * 16 + d], k4.x + k4.y + k4.z + k4.w);
  }

  // folded: oR = oW@rot (blocks 0..31), bR = ob@rot (block 32)
  if (bid < 32) {
    int idx = bid * 512 + tid;
    int row = idx >> 7, col = idx & 127;
    const float* ow = oW + row * 128;
    float acc = 0.f;
#pragma unroll 8
    for (int k = 0; k < 128; k++) acc += ow[k] * rot[k * 128 + col];
    oR[idx] = acc;
  } else if (bid == 32 && tid < 128) {
    float acc = 0.f;
#pragma unroll 8
    for (int k = 0; k < 128; k++) acc += ob[k] * rot[k * 128 + tid];
    bR[tid] = acc;
  }
}

// ===== k_redc: sum the NCPY stripes into ctx/ksum ============================
__global__ __launch_bounds__(512) void k_redc(const float* __restrict__ ctxp,
                                              const float* __restrict__ ksump,
                                              float* __restrict__ ctx,
                                              float* __restrict__ ksum) {
  int idx = blockIdx.x * 512 + threadIdx.x;          // grid 17 -> idx < 8704
  if (idx < 8192) {
    float s = 0.f;
#pragma unroll
    for (int c = 0; c < NCPY; c++) s += ctxp[c * 8192 + idx];
    ctx[idx] = s;
  } else if (idx < 8704) {
    int i2 = idx - 8192;
    float s = 0.f;
#pragma unroll
    for (int c = 0; c < NCPY; c++) s += ksump[c * 512 + i2];
    ksum[i2] = s;
  }
}

// ===== k_mid: attn -> oR(+quant) -> s1s2(+res) -> rms2||gate -> top2+scatter
// (byte-identical to the verified round-0 k_mid)
__global__ __launch_bounds__(512) void k_mid(
    const float* __restrict__ x, const float* __restrict__ qbuf,
    const float* __restrict__ ctx, const float* __restrict__ ksum,
    const float* __restrict__ oR, const float* __restrict__ bR,
    const float* __restrict__ tqs,
    const float* __restrict__ s1W, const float* __restrict__ s1b,
    const float* __restrict__ s2W, const float* __restrict__ s2b,
    const float* __restrict__ g2, const float* __restrict__ gateW,
    const float* __restrict__ gateb,
    float* __restrict__ xnbuf, float* __restrict__ h2buf,
    float* __restrict__ gw, int* __restrict__ tokslot,
    int* __restrict__ slottok, int* __restrict__ cnt) {
  const int tid = threadIdx.x;
  const int j = tid & 127, g = tid >> 7;
  const int lane = tid & 63;
  const int n0 = blockIdx.x * 4;
  const int b = n0 >> 9;

  __shared__ float4 bufA[128], bufB[128];
  __shared__ float4 part[3][128];
  __shared__ float4 gpart[256];
  __shared__ float4 rtmp[2];
  __shared__ float wvS[4][4]; __shared__ int wiS[4][4];
  __shared__ float zS[4][4];

  float xres[4];
  if (tid < 128) {
#pragma unroll
    for (int t = 0; t < 4; t++) xres[t] = x[(n0 + t) * Dd + j];
  }

  ((float*)&bufA[j])[g] = qbuf[(n0 + g) * Dd + j];
  __syncthreads();

  if (tid < 128) {
    int h = j >> 4, e = j & 15;
    const float* cpt = ctx + (b * NH + h) * 256;
    const float* kpt = ksum + (b * NH + h) * 16;
    float num[4] = {0, 0, 0, 0}, den[4] = {0, 0, 0, 0};
#pragma unroll
    for (int d = 0; d < 16; d++) {
      float cx = cpt[d * 16 + e], ks = kpt[d];
      float4 q4 = bufA[h * 16 + d];
      num[0] += q4.x * cx; num[1] += q4.y * cx; num[2] += q4.z * cx; num[3] += q4.w * cx;
      den[0] += q4.x * ks; den[1] += q4.y * ks; den[2] += q4.z * ks; den[3] += q4.w * ks;
    }
#pragma unroll
    for (int t = 0; t < 4; t++) ((float*)&bufB[j])[t] = num[t] / (den[t] + EPSF);
  }
  __syncthreads();

  {
    float a0 = 0, a1 = 0, a2 = 0, a3 = 0;
    const float* Wp = oR + (g * 32) * Dd + j;
#pragma unroll 16
    for (int i = 0; i < 32; i++) {
      float4 h4 = bufB[g * 32 + i];
      float w = Wp[i * Dd];
      a0 += h4.x * w; a1 += h4.y * w; a2 += h4.z * w; a3 += h4.w * w;
    }
    if (g) part[g - 1][j] = make_float4(a0, a1, a2, a3);
    __syncthreads();
    float tot[4];
    if (g == 0) {
      float4 p0 = part[0][j], p1 = part[1][j], p2 = part[2][j];
      float bb = bR[j];
      tot[0] = a0 + p0.x + p1.x + p2.x + bb; tot[1] = a1 + p0.y + p1.y + p2.y + bb;
      tot[2] = a2 + p0.z + p1.z + p2.z + bb; tot[3] = a3 + p0.w + p1.w + p2.w + bb;
      float v[4];
#pragma unroll
      for (int t = 0; t < 4; t++) v[t] = tot[t] * tot[t];
#pragma unroll
      for (int o = 32; o > 0; o >>= 1) {
#pragma unroll
        for (int t = 0; t < 4; t++) v[t] += __shfl_xor(v[t], o, 64);
      }
      if (lane == 0) rtmp[tid >> 6] = make_float4(v[0], v[1], v[2], v[3]);
    }
    __syncthreads();
    if (g == 0) {
      float scj = tqs[j];
#pragma unroll
      for (int t = 0; t < 4; t++) {
        float ss = ((const float*)&rtmp[0])[t] + ((const float*)&rtmp[1])[t];
        float mag = sqrtf(ss * (1.f / 128.f) + EPSF);
        float zc = fminf(fmaxf(tot[t], -mag), mag);
        ((float*)&bufA[j])[t] = zc * scj;
      }
    }
    __syncthreads();
  }

  {
    float a0 = 0, a1 = 0, a2 = 0, a3 = 0;
    const float* Wp = (g < 2 ? s1W : s2W) + ((g & 1) * 64) * Dd + j;
#pragma unroll 16
    for (int i = 0; i < 64; i++) {
      float4 h4 = bufA[(g & 1) * 64 + i];
      float w = Wp[i * Dd];
      a0 += h4.x * w; a1 += h4.y * w; a2 += h4.z * w; a3 += h4.w * w;
    }
    if (g) part[g - 1][j] = make_float4(a0, a1, a2, a3);
    __syncthreads();
    if (g == 0) {
      float b1 = s1b[j], b2 = s2b[j];
      float4 p0 = part[0][j], p1 = part[1][j], p2 = part[2][j];
      float gv[4], uv[4], xn[4], v[4];
      gv[0] = a0 + p0.x + b1; gv[1] = a1 + p0.y + b1;
      gv[2] = a2 + p0.z + b1; gv[3] = a3 + p0.w + b1;
      uv[0] = p1.x + p2.x + b2; uv[1] = p1.y + p2.y + b2;
      uv[2] = p1.z + p2.z + b2; uv[3] = p1.w + p2.w + b2;
      float g2j = g2[j];
#pragma unroll
      for (int t = 0; t < 4; t++) {
        xn[t] = xres[t] + gv[t] * sigm(gv[t]) * uv[t];
        xnbuf[(n0 + t) * Dd + j] = xn[t];
        ((float*)&bufB[j])[t] = g2j * xn[t];
        v[t] = xn[t] * xn[t];
      }
#pragma unroll
      for (int o = 32; o > 0; o >>= 1) {
#pragma unroll
        for (int t = 0; t < 4; t++) v[t] += __shfl_xor(v[t], o, 64);
      }
      if (lane == 0) rtmp[tid >> 6] = make_float4(v[0], v[1], v[2], v[3]);
    }
    __syncthreads();
  }

  float val[4];
  float r2[4];
  {
    int col = tid & 255, kh = tid >> 8;
    float a0 = 0, a1 = 0, a2 = 0, a3 = 0;
    const float* Wp = gateW + (kh * 64) * NE + col;
#pragma unroll 16
    for (int i = 0; i < 64; i++) {
      float4 h4 = bufB[kh * 64 + i];
      float w = Wp[i * NE];
      a0 += h4.x * w; a1 += h4.y * w; a2 += h4.z * w; a3 += h4.w * w;
    }
    if (kh) gpart[col] = make_float4(a0, a1, a2, a3);
    __syncthreads();
#pragma unroll
    for (int t = 0; t < 4; t++) {
      float ss = ((const float*)&rtmp[0])[t] + ((const float*)&rtmp[1])[t];
      r2[t] = rsqrtf(ss * (1.f / 128.f) + EPSF);
    }
    if (!kh) {
      float4 p = gpart[col];
      float bb = gateb[col];
      val[0] = (a0 + p.x) * r2[0] + bb; val[1] = (a1 + p.y) * r2[1] + bb;
      val[2] = (a2 + p.z) * r2[2] + bb; val[3] = (a3 + p.w) * r2[3] + bb;
    }
    if (tid < 128) {
#pragma unroll
      for (int t = 0; t < 4; t++)
        h2buf[(n0 + t) * Dd + j] = ((const float*)&bufB[j])[t] * r2[t];
    }
  }
  __syncthreads();

  float m1[4]; int i1[4];
  {
    if (tid < 256) {
      float bv[4]; int bi[4];
#pragma unroll
      for (int t = 0; t < 4; t++) { bv[t] = val[t]; bi[t] = tid; }
#pragma unroll
      for (int o = 32; o > 0; o >>= 1) {
#pragma unroll
        for (int t = 0; t < 4; t++) {
          float wv = __shfl_xor(bv[t], o, 64);
          int wi = __shfl_xor(bi[t], o, 64);
          if (wv > bv[t] || (wv == bv[t] && wi < bi[t])) { bv[t] = wv; bi[t] = wi; }
        }
      }
      if (lane == 0) {
#pragma unroll
        for (int t = 0; t < 4; t++) { wvS[tid >> 6][t] = bv[t]; wiS[tid >> 6][t] = bi[t]; }
      }
    }
    __syncthreads();
    if (tid < 256) {
#pragma unroll
      for (int t = 0; t < 4; t++) {
        m1[t] = wvS[0][t]; i1[t] = wiS[0][t];
#pragma unroll
        for (int w = 1; w < 4; w++) {
          float cv = wvS[w][t]; int ci = wiS[w][t];
          if (cv > m1[t] || (cv == m1[t] && ci < i1[t])) { m1[t] = cv; i1[t] = ci; }
        }
      }
    }
    __syncthreads();
  }
  float m2[4]; int i2[4];
  {
    if (tid < 256) {
      float bv[4]; int bi[4];
#pragma unroll
      for (int t = 0; t < 4; t++) {
        bv[t] = (tid == i1[t]) ? -INFINITY : val[t];
        bi[t] = tid;
      }
#pragma unroll
      for (int o = 32; o > 0; o >>= 1) {
#pragma unroll
        for (int t = 0; t < 4; t++) {
          float wv = __shfl_xor(bv[t], o, 64);
          int wi = __shfl_xor(bi[t], o, 64);
          if (wv > bv[t] || (wv == bv[t] && wi < bi[t])) { bv[t] = wv; bi[t] = wi; }
        }
      }
      if (lane == 0) {
#pragma unroll
        for (int t = 0; t < 4; t++) { wvS[tid >> 6][t] = bv[t]; wiS[tid >> 6][t] = bi[t]; }
      }
    }
    __syncthreads();
    if (tid < 256) {
#pragma unroll
      for (int t = 0; t < 4; t++) {
        m2[t] = wvS[0][t]; i2[t] = wiS[0][t];
#pragma unroll
        for (int w = 1; w < 4; w++) {
          float cv = wvS[w][t]; int ci = wiS[w][t];
          if (cv > m2[t] || (cv == m2[t] && ci < i2[t])) { m2[t] = cv; i2[t] = ci; }
        }
      }
    }
    __syncthreads();
  }
  {
    if (tid < 256) {
      float v[4];
#pragma unroll
      for (int t = 0; t < 4; t++) v[t] = expf(val[t] - m1[t]);
#pragma unroll
      for (int o = 32; o > 0; o >>= 1) {
#pragma unroll
        for (int t = 0; t < 4; t++) v[t] += __shfl_xor(v[t], o, 64);
      }
      if (lane == 0) {
#pragma unroll
        for (int t = 0; t < 4; t++) zS[tid >> 6][t] = v[t];
      }
    }
    __syncthreads();
  }
  if (tid < 4) {
    int t = tid, tok = n0 + t;
    float Z = zS[0][t] + zS[1][t] + zS[2][t] + zS[3][t];
    float p1 = 1.f / Z;
    float p2 = expf(m2[t] - m1[t]) / Z;
    float s = p1 + p2 + EPSF;
    int e1 = i1[t], e2 = i2[t];
    int s1 = atomicAdd(&cnt[e1], 1); if (s1 > SLOTS - 1) s1 = SLOTS - 1;
    int s2 = atomicAdd(&cnt[e2], 1); if (s2 > SLOTS - 1) s2 = SLOTS - 1;
    int sl1 = e1 * SLOTS + s1, sl2 = e2 * SLOTS + s2;
    slottok[sl1] = tok; slottok[sl2] = tok;
    tokslot[tok * 2] = sl1; tokslot[tok * 2 + 1] = sl2;
    gw[tok * 2] = p1 / s; gw[tok * 2 + 1] = p2 / s;
  }
}

// ===== k_exp: expert-major, 2 blocks per expert (chunk-split) ===============
__global__ __launch_bounds__(512) void k_exp(const float* __restrict__ h2buf,
                                             const int* __restrict__ slottok,
                                             const int* __restrict__ cnt,
                                             const float* __restrict__ expW,
                                             float* __restrict__ ybuf) {
  const int e = blockIdx.x >> 1, sub = blockIdx.x & 1;
  int n = cnt[e]; if (n > SLOTS) n = SLOTS;
  const int base = e * SLOTS;
  const int tid = threadIdx.x;
  const int j = tid & 127, g = tid >> 7;
  __shared__ __align__(16) float hT[128 * 20];
  const float* Wp = expW + (size_t)e * Dd * Dd + j;
  for (int t0 = sub * 16; t0 < n; t0 += 32) {
    int m = n - t0; if (m > 16) m = 16;
    __syncthreads();
    for (int tt = g; tt < m; tt += 4) {
      int tok = slottok[base + t0 + tt];
      hT[j * 20 + tt] = h2buf[tok * Dd + j];
    }
    __syncthreads();
    float acc[4] = {0, 0, 0, 0};
#pragma unroll 8
    for (int i = 0; i < 128; i++) {
      float w = Wp[i * Dd];
      float4 h4 = *(const float4*)&hT[i * 20 + g * 4];
      acc[0] += h4.x * w; acc[1] += h4.y * w; acc[2] += h4.z * w; acc[3] += h4.w * w;
    }
#pragma unroll
    for (int k = 0; k < 4; k++) {
      int tt = g * 4 + k;
      if (tt < m) ybuf[(size_t)(base + t0 + tt) * Dd + j] = acc[k];
    }
  }
}

// ===== k_post (byte-identical to verified round-0 k_post) ====================
__global__ __launch_bounds__(512) void k_post(
    const float* __restrict__ xnbuf, const float* __restrict__ ybuf,
    const int* __restrict__ tokslot, const float* __restrict__ gw,
    const float* __restrict__ m1W, const float* __restrict__ m1b,
    const float* __restrict__ m2W, const float* __restrict__ m2b,
    float* __restrict__ out) {
  const int tid = threadIdx.x;
  const int j = tid & 127, g = tid >> 7;
  const int lane = tid & 63;
  const int n0 = blockIdx.x * 4;

  __shared__ float4 y1T[128], y2T[128], inT[128], sT[128];
  __shared__ float4 part[3][128];
  __shared__ float4 rtmp[2];
  __shared__ int sSlot[4][2];
  __shared__ float sWt[4][2];

  if (tid < 4) {
    sSlot[tid][0] = tokslot[(n0 + tid) * 2];
    sSlot[tid][1] = tokslot[(n0 + tid) * 2 + 1];
    sWt[tid][0] = gw[(n0 + tid) * 2];
    sWt[tid][1] = gw[(n0 + tid) * 2 + 1];
  }
  __syncthreads();

  {
    float y1 = ybuf[(size_t)sSlot[g][0] * Dd + j];
    float y2 = ybuf[(size_t)sSlot[g][1] * Dd + j];
    ((float*)&y1T[j])[g] = y1;
    ((float*)&y2T[j])[g] = y2;
    ((float*)&inT[j])[g] = sWt[g][0] * y1 + sWt[g][1] * y2;
  }
  __syncthreads();

  {
    float a0 = 0, a1 = 0, a2 = 0, a3 = 0;
    const float* Wp = (g < 2 ? m1W : m2W) + ((g & 1) * 64) * Dd + j;
#pragma unroll 16
    for (int i = 0; i < 64; i++) {
      float4 h4 = inT[(g & 1) * 64 + i];
      float w = Wp[i * Dd];
      a0 += h4.x * w; a1 += h4.y * w; a2 += h4.z * w; a3 += h4.w * w;
    }
    if (g) part[g - 1][j] = make_float4(a0, a1, a2, a3);
    __syncthreads();
    if (g == 0) {
      float b1 = m1b[j], b2 = m2b[j];
      float4 p0 = part[0][j], p1 = part[1][j], p2 = part[2][j];
      float gv[4], uv[4];
      gv[0] = a0 + p0.x + b1; gv[1] = a1 + p0.y + b1;
      gv[2] = a2 + p0.z + b1; gv[3] = a3 + p0.w + b1;
      uv[0] = p1.x + p2.x + b2; uv[1] = p1.y + p2.y + b2;
      uv[2] = p1.z + p2.z + b2; uv[3] = p1.w + p2.w + b2;
#pragma unroll
      for (int t = 0; t < 4; t++) {
        float sv = gv[t] * sigm(gv[t]) * uv[t];
        ((float*)&sT[j])[t] = sv;
        out[(n0 + t) * Dd + j] = xnbuf[(n0 + t) * Dd + j] + sv;
      }
    }
    __syncthreads();
  }

  if (tid < 128) {
    float v[4];
#pragma unroll
    for (int t = 0; t < 4; t++) {
      float sv = ((const float*)&sT[j])[t];
      float d1 = ((const float*)&y1T[j])[t] - sv;
      float d2 = ((const float*)&y2T[j])[t] - sv;
      v[t] = sWt[t][0] * d1 * d1 + sWt[t][1] * d2 * d2;
    }
#pragma unroll
    for (int o = 32; o > 0; o >>= 1) {
#pragma unroll
      for (int t = 0; t < 4; t++) v[t] += __shfl_xor(v[t], o, 64);
    }
    if (lane == 0) rtmp[tid >> 6] = make_float4(v[0], v[1], v[2], v[3]);
  }
  __syncthreads();
  if (tid < 4) {
    float s = ((const float*)&rtmp[0])[tid] + ((const float*)&rtmp[1])[tid];
    out[NTOK * Dd + n0 + tid] = expf(-s * (1.f / 128.f));
  }
}

// ============================================================================
extern "C" void kernel_launch(void* const* d_in, const int* in_sizes, int n_in,
                              void* d_out, int out_size, void* d_ws, size_t ws_size,
                              hipStream_t stream) {
  const float* x   = (const float*)d_in[0];
  const float* g1  = (const float*)d_in[1];
  const float* qW  = (const float*)d_in[2];
  const float* qb  = (const float*)d_in[3];
  const float* kdW = (const float*)d_in[4];
  const float* kdb = (const float*)d_in[5];
  const float* kuW = (const float*)d_in[6];
  const float* kub = (const float*)d_in[7];
  const float* oW  = (const float*)d_in[8];
  const float* ob  = (const float*)d_in[9];
  const float* rot = (const float*)d_in[10];
  const float* tqs = (const float*)d_in[11];
  const float* s1W = (const float*)d_in[12];
  const float* s1b = (const float*)d_in[13];
  const float* s2W = (const float*)d_in[14];
  const float* s2b = (const float*)d_in[15];
  const float* g2  = (const float*)d_in[16];
  const float* gW  = (const float*)d_in[17];
  const float* gb  = (const float*)d_in[18];
  const float* eW  = (const float*)d_in[19];
  const float* m1W = (const float*)d_in[20];
  const float* m1b = (const float*)d_in[21];
  const float* m2W = (const float*)d_in[22];
  const float* m2b = (const float*)d_in[23];
  float* out = (float*)d_out;
  float* ws  = (float*)d_ws;

  float* ctxp    = ws;                       // 16*8192 = 131072
  float* ksump   = ws + 131072;              // 16*512  = 8192
  float* ctx     = ws + 139264;              // 8192
  float* ksum    = ws + 147456;              // 512
  float* oR      = ws + 147968;              // 16384
  float* bR      = ws + 164352;              // 128
  float* qbuf    = ws + 164480;              // 262144
  float* xnbuf   = ws + 426624;              // 262144
  float* h2buf   = ws + 688768;              // 262144
  float* gw      = ws + 950912;              // 4096
  int*   cnt     = (int*)(ws + 955008);      // 256
  int*   tokslot = (int*)(ws + 955264);      // 4096
  int*   slottok = (int*)(ws + 959360);      // 65536
  float* ybuf    = ws + 1024896;             // 256*256*128 = 8388608

  k_zero<<<273, 512, 0, stream>>>(ctxp, ksump, cnt);
  k_pre<<<NTOK / 4, 512, 0, stream>>>(x, g1, qW, qb, kdW, kdb, kuW, kub,
                                      oW, ob, rot, qbuf, ctxp, ksump, oR, bR);
  k_redc<<<17, 512, 0, stream>>>(ctxp, ksump, ctx, ksum);
  k_mid<<<NTOK / 4, 512, 0, stream>>>(x, qbuf, ctx, ksum, oR, bR, tqs,
                                      s1W, s1b, s2W, s2b, g2, gW, gb,
                                      xnbuf, h2buf, gw, tokslot, slottok, cnt);
  k_exp<<<NE * 2, 512, 0, stream>>>(h2buf, slottok, cnt, eW, ybuf);
  k_post<<<NTOK / 4, 512, 0, stream>>>(xnbuf, ybuf, tokslot, gw,
                                       m1W, m1b, m2W, m2b, out);
}

// Round 6
// 162.528 us; speedup vs baseline: 1.2178x; 1.1372x over previous
//
#include <hip/hip_runtime.h>
#include <math.h>

static constexpr int Dd    = 128;
static constexpr int NH    = 8;
static constexpr int NE    = 256;
static constexpr int RR    = 32;
static constexpr int TT    = 512;
static constexpr int NTOK  = 2048;
static constexpr int SLOTS = 256;
#define EPSF 1e-6f

// flag layout (ints): [0..3] ctx_done per batch (target 64)
//                     [4]    route_done        (target 512)
//                     [5..260] exp_done per expert (target 2)
static constexpr int FD_CTX   = 0;
static constexpr int FD_ROUTE = 4;
static constexpr int FD_EXP   = 5;
static constexpr int NFLAGS   = 261;

__device__ __forceinline__ float elu1(float v) { return v > 0.f ? v + 1.f : expf(v); }
__device__ __forceinline__ float sigm(float v) { return 1.f / (1.f + expf(-v)); }

__device__ __forceinline__ void flag_add(int* p) {
  __hip_atomic_fetch_add(p, 1, __ATOMIC_RELEASE, __HIP_MEMORY_SCOPE_AGENT);
}
__device__ __forceinline__ void flag_wait(int* p, int tgt) {
  int c = 0;
  while (__hip_atomic_load(p, __ATOMIC_ACQUIRE, __HIP_MEMORY_SCOPE_AGENT) < tgt) {
    __builtin_amdgcn_s_sleep(2);
    if (++c > (1 << 27)) break;   // safety valve against hangs
  }
}

// ===== k_pre: rmsnorm1 + q + kd + ku -> qbuf,kvbuf; zero accums/flags; oR/bR
__global__ __launch_bounds__(512) void k_pre(
    const float* __restrict__ x, const float* __restrict__ g1,
    const float* __restrict__ qW, const float* __restrict__ qb,
    const float* __restrict__ kdW, const float* __restrict__ kdb,
    const float* __restrict__ kuW, const float* __restrict__ kub,
    const float* __restrict__ oW, const float* __restrict__ ob,
    const float* __restrict__ rot,
    float* __restrict__ qbuf, float* __restrict__ kvbuf,
    float* __restrict__ ctx, float* __restrict__ ksum,
    int* __restrict__ cnt, int* __restrict__ flags,
    float* __restrict__ oR, float* __restrict__ bR) {
  const int tid = threadIdx.x;
  const int bid = blockIdx.x;
  const int j = tid & 127, g = tid >> 7;
  const int lane = tid & 63;
  const int n0 = bid * 4;

  __shared__ float4 h1T[128];
  __shared__ float4 part[3][128];
  __shared__ float4 kpart[8][32];
  __shared__ float4 kdT[32];
  __shared__ float4 kupart[256];
  __shared__ float4 rtmp[2];

  if (bid == 0) {   // zero accumulators + flags; ordered before k_rest by boundary
    for (int i = tid; i < 32 * 256; i += 512) ctx[i] = 0.f;
    ksum[tid] = 0.f;
    if (tid < NE) cnt[tid] = 0;
    if (tid < NFLAGS) flags[tid] = 0;
  }

  float xv[4];
  if (tid < 128) {
    float v[4];
#pragma unroll
    for (int t = 0; t < 4; t++) { xv[t] = x[(n0 + t) * Dd + j]; v[t] = xv[t] * xv[t]; }
#pragma unroll
    for (int o = 32; o > 0; o >>= 1) {
#pragma unroll
      for (int t = 0; t < 4; t++) v[t] += __shfl_xor(v[t], o, 64);
    }
    if (lane == 0) rtmp[tid >> 6] = make_float4(v[0], v[1], v[2], v[3]);
  }
  __syncthreads();
  if (tid < 128) {
    float g1j = g1[j];
#pragma unroll
    for (int t = 0; t < 4; t++) {
      float ss = ((const float*)&rtmp[0])[t] + ((const float*)&rtmp[1])[t];
      ((float*)&h1T[j])[t] = g1j * xv[t] * rsqrtf(ss * (1.f / 128.f) + EPSF);
    }
  }
  __syncthreads();

  {
    float a0 = 0, a1 = 0, a2 = 0, a3 = 0;
    const float* Wp = qW + (g * 32) * Dd + j;
#pragma unroll 16
    for (int i = 0; i < 32; i++) {
      float4 h4 = h1T[g * 32 + i];
      float w = Wp[i * Dd];
      a0 += h4.x * w; a1 += h4.y * w; a2 += h4.z * w; a3 += h4.w * w;
    }
    if (g) part[g - 1][j] = make_float4(a0, a1, a2, a3);
    __syncthreads();
    if (g == 0) {
      float4 p0 = part[0][j], p1 = part[1][j], p2 = part[2][j];
      float bb = qb[j];
      qbuf[(n0 + 0) * Dd + j] = elu1(a0 + p0.x + p1.x + p2.x + bb);
      qbuf[(n0 + 1) * Dd + j] = elu1(a1 + p0.y + p1.y + p2.y + bb);
      qbuf[(n0 + 2) * Dd + j] = elu1(a2 + p0.z + p1.z + p2.z + bb);
      qbuf[(n0 + 3) * Dd + j] = elu1(a3 + p0.w + p1.w + p2.w + bb);
    }
    __syncthreads();
  }

  if (tid < 256) {
    int col = tid & 31, ksp = tid >> 5;
    float a0 = 0, a1 = 0, a2 = 0, a3 = 0;
    const float* Wp = kdW + (ksp * 16) * RR + col;
#pragma unroll
    for (int i = 0; i < 16; i++) {
      float4 h4 = h1T[ksp * 16 + i];
      float w = Wp[i * RR];
      a0 += h4.x * w; a1 += h4.y * w; a2 += h4.z * w; a3 += h4.w * w;
    }
    kpart[ksp][col] = make_float4(a0, a1, a2, a3);
  }
  __syncthreads();
  if (tid < 32) {
    float bb = kdb[tid];
    float s0 = bb, s1 = bb, s2 = bb, s3 = bb;
#pragma unroll
    for (int k = 0; k < 8; k++) {
      float4 p = kpart[k][tid];
      s0 += p.x; s1 += p.y; s2 += p.z; s3 += p.w;
    }
    kdT[tid] = make_float4(s0, s1, s2, s3);
  }
  __syncthreads();

  {
    int col = tid & 255, kh = tid >> 8;
    float a0 = 0, a1 = 0, a2 = 0, a3 = 0;
    const float* Wp = kuW + (kh * 16) * 256 + col;
#pragma unroll
    for (int r = 0; r < 16; r++) {
      float4 k4 = kdT[kh * 16 + r];
      float w = Wp[r * 256];
      a0 += k4.x * w; a1 += k4.y * w; a2 += k4.z * w; a3 += k4.w * w;
    }
    if (kh) kupart[col] = make_float4(a0, a1, a2, a3);
    __syncthreads();
    if (!kh) {
      float4 p = kupart[col];
      float bb = kub[col];
      bool isk = (col & 31) < 16;
      float v0 = a0 + p.x + bb, v1 = a1 + p.y + bb, v2 = a2 + p.z + bb, v3 = a3 + p.w + bb;
      kvbuf[(n0 + 0) * 256 + col] = isk ? elu1(v0) : v0;
      kvbuf[(n0 + 1) * 256 + col] = isk ? elu1(v1) : v1;
      kvbuf[(n0 + 2) * 256 + col] = isk ? elu1(v2) : v2;
      kvbuf[(n0 + 3) * 256 + col] = isk ? elu1(v3) : v3;
    }
  }

  // folded: oR = oW@rot (blocks 0..31), bR = ob@rot (block 32)
  if (bid < 32) {
    int idx = bid * 512 + tid;
    int row = idx >> 7, col = idx & 127;
    const float* ow = oW + row * 128;
    float acc = 0.f;
#pragma unroll 8
    for (int k = 0; k < 128; k++) acc += ow[k] * rot[k * 128 + col];
    oR[idx] = acc;
  } else if (bid == 32 && tid < 128) {
    float acc = 0.f;
#pragma unroll 8
    for (int k = 0; k < 128; k++) acc += ob[k] * rot[k * 128 + tid];
    bR[tid] = acc;
  }
}

// ===== k_rest: ctx(role) -> [flag] -> mid -> [flag] -> exp -> [flag] -> post
struct RParams {
  const float *x, *qbuf, *kvbuf, *oR, *bR, *tqs;
  const float *s1W, *s1b, *s2W, *s2b, *g2, *gateW, *gateb, *expW;
  const float *m1W, *m1b, *m2W, *m2b;
  float *ctx, *ksum, *h2buf, *ybuf, *out;
  int *cnt, *slottok, *flags;
};

__global__ __launch_bounds__(512, 4) void k_rest(RParams P) {
  const int tid = threadIdx.x;
  const int bid = blockIdx.x;
  const int j = tid & 127, g = tid >> 7;
  const int lane = tid & 63;
  const int n0 = bid * 4;
  const int b = bid >> 7;

  __shared__ float sh[64 * 32];                 // ctx staging (role A)
  __shared__ float4 bufA[128], bufB[128];
  __shared__ float4 part[3][128];
  __shared__ float4 gpart[256];
  __shared__ float4 rtmp[2];
  __shared__ float wvS[4][4]; __shared__ int wiS[4][4];
  __shared__ float zS[4][4];
  __shared__ int sE[4][2]; __shared__ int sSlot[4][2]; __shared__ float sWt[4][2];
  __shared__ __align__(16) float hT[128 * 20];  // expert staging
  __shared__ float4 y1T[128], y2T[128], inT[128], sT[128];

  // x residual + q load (independent of ctx)
  float xres[4];
  if (tid < 128) {
#pragma unroll
    for (int t = 0; t < 4; t++) xres[t] = P.x[(n0 + t) * Dd + j];
  }
  ((float*)&bufA[j])[g] = P.qbuf[(n0 + g) * Dd + j];

  // ---- role A: ctx/ksum accumulation (blocks 0..255), verbatim R0 k_ctx ----
  if (bid < 256) {
    const int bh = bid >> 3, c = bid & 7;
    const int bb = bh >> 3, h = bh & 7;
#pragma unroll
    for (int r = 0; r < 4; r++) {
      int lin = r * 512 + tid;
      int tok = lin >> 5, off = lin & 31;
      sh[lin] = P.kvbuf[((bb * TT + c * 64 + tok) * 256) + h * 32 + off];
    }
    __syncthreads();
    if (tid < 256) {
      const int d = tid >> 4, e = tid & 15;
      float acc = 0.f, ks = 0.f;
#pragma unroll 4
      for (int t = 0; t < 64; t++) {
        float kk = sh[t * 32 + d];
        acc += kk * sh[t * 32 + 16 + e];
        ks += kk;
      }
      atomicAdd(&P.ctx[bh * 256 + d * 16 + e], acc);
      if (e == 0) atomicAdd(&P.ksum[bh * 16 + d], ks);
    }
    __threadfence();
    __syncthreads();
    if (tid == 0) flag_add(&P.flags[FD_CTX + bb]);
  }

  // ---- wait for own batch's ctx ----
  if (tid == 0) flag_wait(&P.flags[FD_CTX + b], 64);
  __syncthreads();
  __threadfence();

  // ---- mid: attn -> quant -> s1s2 -> rms2||gate -> top2 + scatter ----
  if (tid < 128) {
    int h = j >> 4, e = j & 15;
    const float* cpt = P.ctx + (b * NH + h) * 256;
    const float* kpt = P.ksum + (b * NH + h) * 16;
    float num[4] = {0, 0, 0, 0}, den[4] = {0, 0, 0, 0};
#pragma unroll
    for (int d = 0; d < 16; d++) {
      float cx = cpt[d * 16 + e], ks = kpt[d];
      float4 q4 = bufA[h * 16 + d];
      num[0] += q4.x * cx; num[1] += q4.y * cx; num[2] += q4.z * cx; num[3] += q4.w * cx;
      den[0] += q4.x * ks; den[1] += q4.y * ks; den[2] += q4.z * ks; den[3] += q4.w * ks;
    }
#pragma unroll
    for (int t = 0; t < 4; t++) ((float*)&bufB[j])[t] = num[t] / (den[t] + EPSF);
  }
  __syncthreads();

  {
    float a0 = 0, a1 = 0, a2 = 0, a3 = 0;
    const float* Wp = P.oR + (g * 32) * Dd + j;
#pragma unroll 16
    for (int i = 0; i < 32; i++) {
      float4 h4 = bufB[g * 32 + i];
      float w = Wp[i * Dd];
      a0 += h4.x * w; a1 += h4.y * w; a2 += h4.z * w; a3 += h4.w * w;
    }
    if (g) part[g - 1][j] = make_float4(a0, a1, a2, a3);
    __syncthreads();
    float tot[4];
    if (g == 0) {
      float4 p0 = part[0][j], p1 = part[1][j], p2 = part[2][j];
      float bb = P.bR[j];
      tot[0] = a0 + p0.x + p1.x + p2.x + bb; tot[1] = a1 + p0.y + p1.y + p2.y + bb;
      tot[2] = a2 + p0.z + p1.z + p2.z + bb; tot[3] = a3 + p0.w + p1.w + p2.w + bb;
      float v[4];
#pragma unroll
      for (int t = 0; t < 4; t++) v[t] = tot[t] * tot[t];
#pragma unroll
      for (int o = 32; o > 0; o >>= 1) {
#pragma unroll
        for (int t = 0; t < 4; t++) v[t] += __shfl_xor(v[t], o, 64);
      }
      if (lane == 0) rtmp[tid >> 6] = make_float4(v[0], v[1], v[2], v[3]);
    }
    __syncthreads();
    if (g == 0) {
      float scj = P.tqs[j];
#pragma unroll
      for (int t = 0; t < 4; t++) {
        float ss = ((const float*)&rtmp[0])[t] + ((const float*)&rtmp[1])[t];
        float mag = sqrtf(ss * (1.f / 128.f) + EPSF);
        float zc = fminf(fmaxf(tot[t], -mag), mag);
        ((float*)&bufA[j])[t] = zc * scj;
      }
    }
    __syncthreads();
  }

  float xn[4] = {0.f, 0.f, 0.f, 0.f};
  {
    float a0 = 0, a1 = 0, a2 = 0, a3 = 0;
    const float* Wp = (g < 2 ? P.s1W : P.s2W) + ((g & 1) * 64) * Dd + j;
#pragma unroll 16
    for (int i = 0; i < 64; i++) {
      float4 h4 = bufA[(g & 1) * 64 + i];
      float w = Wp[i * Dd];
      a0 += h4.x * w; a1 += h4.y * w; a2 += h4.z * w; a3 += h4.w * w;
    }
    if (g) part[g - 1][j] = make_float4(a0, a1, a2, a3);
    __syncthreads();
    if (g == 0) {
      float b1 = P.s1b[j], b2 = P.s2b[j];
      float4 p0 = part[0][j], p1 = part[1][j], p2 = part[2][j];
      float gv[4], uv[4], v[4];
      gv[0] = a0 + p0.x + b1; gv[1] = a1 + p0.y + b1;
      gv[2] = a2 + p0.z + b1; gv[3] = a3 + p0.w + b1;
      uv[0] = p1.x + p2.x + b2; uv[1] = p1.y + p2.y + b2;
      uv[2] = p1.z + p2.z + b2; uv[3] = p1.w + p2.w + b2;
      float g2j = P.g2[j];
#pragma unroll
      for (int t = 0; t < 4; t++) {
        xn[t] = xres[t] + gv[t] * sigm(gv[t]) * uv[t];   // regs -> post
        ((float*)&bufB[j])[t] = g2j * xn[t];
        v[t] = xn[t] * xn[t];
      }
#pragma unroll
      for (int o = 32; o > 0; o >>= 1) {
#pragma unroll
        for (int t = 0; t < 4; t++) v[t] += __shfl_xor(v[t], o, 64);
      }
      if (lane == 0) rtmp[tid >> 6] = make_float4(v[0], v[1], v[2], v[3]);
    }
    __syncthreads();
  }

  float val[4]; float r2v[4];
  {
    int col = tid & 255, kh = tid >> 8;
    float a0 = 0, a1 = 0, a2 = 0, a3 = 0;
    const float* Wp = P.gateW + (kh * 64) * NE + col;
#pragma unroll 16
    for (int i = 0; i < 64; i++) {
      float4 h4 = bufB[kh * 64 + i];
      float w = Wp[i * NE];
      a0 += h4.x * w; a1 += h4.y * w; a2 += h4.z * w; a3 += h4.w * w;
    }
    if (kh) gpart[col] = make_float4(a0, a1, a2, a3);
    __syncthreads();
#pragma unroll
    for (int t = 0; t < 4; t++) {
      float ss = ((const float*)&rtmp[0])[t] + ((const float*)&rtmp[1])[t];
      r2v[t] = rsqrtf(ss * (1.f / 128.f) + EPSF);
    }
    if (!kh) {
      float4 p = gpart[col];
      float bb = P.gateb[col];
      val[0] = (a0 + p.x) * r2v[0] + bb; val[1] = (a1 + p.y) * r2v[1] + bb;
      val[2] = (a2 + p.z) * r2v[2] + bb; val[3] = (a3 + p.w) * r2v[3] + bb;
    }
    if (tid < 128) {
#pragma unroll
      for (int t = 0; t < 4; t++)
        P.h2buf[(n0 + t) * Dd + j] = ((const float*)&bufB[j])[t] * r2v[t];
    }
  }
  __syncthreads();

  float m1[4]; int i1[4];
  {
    if (tid < 256) {
      float bv[4]; int bi[4];
#pragma unroll
      for (int t = 0; t < 4; t++) { bv[t] = val[t]; bi[t] = tid; }
#pragma unroll
      for (int o = 32; o > 0; o >>= 1) {
#pragma unroll
        for (int t = 0; t < 4; t++) {
          float wv = __shfl_xor(bv[t], o, 64);
          int wi = __shfl_xor(bi[t], o, 64);
          if (wv > bv[t] || (wv == bv[t] && wi < bi[t])) { bv[t] = wv; bi[t] = wi; }
        }
      }
      if (lane == 0) {
#pragma unroll
        for (int t = 0; t < 4; t++) { wvS[tid >> 6][t] = bv[t]; wiS[tid >> 6][t] = bi[t]; }
      }
    }
    __syncthreads();
    if (tid < 256) {
#pragma unroll
      for (int t = 0; t < 4; t++) {
        m1[t] = wvS[0][t]; i1[t] = wiS[0][t];
#pragma unroll
        for (int w = 1; w < 4; w++) {
          float cv = wvS[w][t]; int ci = wiS[w][t];
          if (cv > m1[t] || (cv == m1[t] && ci < i1[t])) { m1[t] = cv; i1[t] = ci; }
        }
      }
    }
    __syncthreads();
  }
  float m2[4]; int i2[4];
  {
    if (tid < 256) {
      float bv[4]; int bi[4];
#pragma unroll
      for (int t = 0; t < 4; t++) {
        bv[t] = (tid == i1[t]) ? -INFINITY : val[t];
        bi[t] = tid;
      }
#pragma unroll
      for (int o = 32; o > 0; o >>= 1) {
#pragma unroll
        for (int t = 0; t < 4; t++) {
          float wv = __shfl_xor(bv[t], o, 64);
          int wi = __shfl_xor(bi[t], o, 64);
          if (wv > bv[t] || (wv == bv[t] && wi < bi[t])) { bv[t] = wv; bi[t] = wi; }
        }
      }
      if (lane == 0) {
#pragma unroll
        for (int t = 0; t < 4; t++) { wvS[tid >> 6][t] = bv[t]; wiS[tid >> 6][t] = bi[t]; }
      }
    }
    __syncthreads();
    if (tid < 256) {
#pragma unroll
      for (int t = 0; t < 4; t++) {
        m2[t] = wvS[0][t]; i2[t] = wiS[0][t];
#pragma unroll
        for (int w = 1; w < 4; w++) {
          float cv = wvS[w][t]; int ci = wiS[w][t];
          if (cv > m2[t] || (cv == m2[t] && ci < i2[t])) { m2[t] = cv; i2[t] = ci; }
        }
      }
    }
    __syncthreads();
  }
  {
    if (tid < 256) {
      float v[4];
#pragma unroll
      for (int t = 0; t < 4; t++) v[t] = expf(val[t] - m1[t]);
#pragma unroll
      for (int o = 32; o > 0; o >>= 1) {
#pragma unroll
        for (int t = 0; t < 4; t++) v[t] += __shfl_xor(v[t], o, 64);
      }
      if (lane == 0) {
#pragma unroll
        for (int t = 0; t < 4; t++) zS[tid >> 6][t] = v[t];
      }
    }
    __syncthreads();
  }
  if (tid < 4) {
    int t = tid, tok = n0 + t;
    float Z = zS[0][t] + zS[1][t] + zS[2][t] + zS[3][t];
    float p1 = 1.f / Z;
    float p2 = expf(m2[t] - m1[t]) / Z;
    float s = p1 + p2 + EPSF;
    int e1 = i1[t], e2 = i2[t];
    int s1 = atomicAdd(&P.cnt[e1], 1); if (s1 > SLOTS - 1) s1 = SLOTS - 1;
    int s2 = atomicAdd(&P.cnt[e2], 1); if (s2 > SLOTS - 1) s2 = SLOTS - 1;
    int sl1 = e1 * SLOTS + s1, sl2 = e2 * SLOTS + s2;
    P.slottok[sl1] = tok; P.slottok[sl2] = tok;
    sE[t][0] = e1; sE[t][1] = e2;
    sSlot[t][0] = sl1; sSlot[t][1] = sl2;
    sWt[t][0] = p1 / s; sWt[t][1] = p2 / s;
  }

  // ---- publish routing, wait for all 512 blocks ----
  __threadfence();
  __syncthreads();
  if (tid == 0) {
    flag_add(&P.flags[FD_ROUTE]);
    flag_wait(&P.flags[FD_ROUTE], 512);
  }
  __syncthreads();
  __threadfence();

  // ---- expert-major compute: e = bid>>1, 2 blocks/expert ----
  {
    const int e = bid >> 1, sub = bid & 1;
    int n = __hip_atomic_load(&P.cnt[e], __ATOMIC_RELAXED, __HIP_MEMORY_SCOPE_AGENT);
    if (n > SLOTS) n = SLOTS;
    const int base = e * SLOTS;
    const float* Wp = P.expW + (size_t)e * Dd * Dd + j;
    for (int t0 = sub * 16; t0 < n; t0 += 32) {
      int m = n - t0; if (m > 16) m = 16;
      __syncthreads();
      for (int tt = g; tt < m; tt += 4) {
        int tok = P.slottok[base + t0 + tt];
        hT[j * 20 + tt] = P.h2buf[tok * Dd + j];
      }
      __syncthreads();
      float acc[4] = {0, 0, 0, 0};
#pragma unroll 8
      for (int i = 0; i < 128; i++) {
        float w = Wp[i * Dd];
        float4 h4 = *(const float4*)&hT[i * 20 + g * 4];
        acc[0] += h4.x * w; acc[1] += h4.y * w; acc[2] += h4.z * w; acc[3] += h4.w * w;
      }
#pragma unroll
      for (int k = 0; k < 4; k++) {
        int tt = g * 4 + k;
        if (tt < m) P.ybuf[(size_t)(base + t0 + tt) * Dd + j] = acc[k];
      }
    }
    __threadfence();
    __syncthreads();
    if (tid == 0) flag_add(&P.flags[FD_EXP + e]);
  }

  // ---- wait for this block's tokens' experts ----
  if (tid < 8) {
    int t = tid >> 1, sl = tid & 1;
    flag_wait(&P.flags[FD_EXP + sE[t][sl]], 2);
  }
  __syncthreads();
  __threadfence();

  // ---- post: gather y -> m1/m2 swiglu -> out + consensus ----
  {
    float y1 = P.ybuf[(size_t)sSlot[g][0] * Dd + j];
    float y2 = P.ybuf[(size_t)sSlot[g][1] * Dd + j];
    ((float*)&y1T[j])[g] = y1;
    ((float*)&y2T[j])[g] = y2;
    ((float*)&inT[j])[g] = sWt[g][0] * y1 + sWt[g][1] * y2;
  }
  __syncthreads();

  {
    float a0 = 0, a1 = 0, a2 = 0, a3 = 0;
    const float* Wp = (g < 2 ? P.m1W : P.m2W) + ((g & 1) * 64) * Dd + j;
#pragma unroll 16
    for (int i = 0; i < 64; i++) {
      float4 h4 = inT[(g & 1) * 64 + i];
      float w = Wp[i * Dd];
      a0 += h4.x * w; a1 += h4.y * w; a2 += h4.z * w; a3 += h4.w * w;
    }
    if (g) part[g - 1][j] = make_float4(a0, a1, a2, a3);
    __syncthreads();
    if (g == 0) {
      float b1 = P.m1b[j], b2 = P.m2b[j];
      float4 p0 = part[0][j], p1 = part[1][j], p2 = part[2][j];
      float gv[4], uv[4];
      gv[0] = a0 + p0.x + b1; gv[1] = a1 + p0.y + b1;
      gv[2] = a2 + p0.z + b1; gv[3] = a3 + p0.w + b1;
      uv[0] = p1.x + p2.x + b2; uv[1] = p1.y + p2.y + b2;
      uv[2] = p1.z + p2.z + b2; uv[3] = p1.w + p2.w + b2;
#pragma unroll
      for (int t = 0; t < 4; t++) {
        float sv = gv[t] * sigm(gv[t]) * uv[t];
        ((float*)&sT[j])[t] = sv;
        P.out[(n0 + t) * Dd + j] = xn[t] + sv;
      }
    }
    __syncthreads();
  }

  if (tid < 128) {
    float v[4];
#pragma unroll
    for (int t = 0; t < 4; t++) {
      float sv = ((const float*)&sT[j])[t];
      float d1 = ((const float*)&y1T[j])[t] - sv;
      float d2 = ((const float*)&y2T[j])[t] - sv;
      v[t] = sWt[t][0] * d1 * d1 + sWt[t][1] * d2 * d2;
    }
#pragma unroll
    for (int o = 32; o > 0; o >>= 1) {
#pragma unroll
      for (int t = 0; t < 4; t++) v[t] += __shfl_xor(v[t], o, 64);
    }
    if (lane == 0) rtmp[tid >> 6] = make_float4(v[0], v[1], v[2], v[3]);
  }
  __syncthreads();
  if (tid < 4) {
    float s = ((const float*)&rtmp[0])[tid] + ((const float*)&rtmp[1])[tid];
    P.out[NTOK * Dd + n0 + tid] = expf(-s * (1.f / 128.f));
  }
}

// ============================================================================
// Fallback path (if cooperative launch refused): verified R0 pipeline pieces.
// ============================================================================
__global__ __launch_bounds__(256) void k_ctx_fb(const float* __restrict__ kv,
                                                float* __restrict__ ctx,
                                                float* __restrict__ ksum) {
  const int blk = blockIdx.x;
  const int tid = threadIdx.x;
  const int bh = blk >> 3, c = blk & 7;
  const int b = bh >> 3, h = bh & 7;
  const int d = tid >> 4, e = tid & 15;
  __shared__ float sh[64 * 32];
#pragma unroll
  for (int r = 0; r < 8; r++) {
    int lin = r * 256 + tid;
    int tok = lin >> 5, off = lin & 31;
    sh[lin] = kv[((b * TT + c * 64 + tok) * 256) + h * 32 + off];
  }
  __syncthreads();
  float acc = 0.f, ks = 0.f;
#pragma unroll 4
  for (int t = 0; t < 64; t++) {
    float kk = sh[t * 32 + d];
    acc += kk * sh[t * 32 + 16 + e];
    ks += kk;
  }
  atomicAdd(&ctx[bh * 256 + d * 16 + e], acc);
  if (e == 0) atomicAdd(&ksum[bh * 16 + d], ks);
}

__global__ __launch_bounds__(512) void k_mid_fb(
    const float* __restrict__ x, const float* __restrict__ qbuf,
    const float* __restrict__ ctx, const float* __restrict__ ksum,
    const float* __restrict__ oR, const float* __restrict__ bR,
    const float* __restrict__ tqs,
    const float* __restrict__ s1W, const float* __restrict__ s1b,
    const float* __restrict__ s2W, const float* __restrict__ s2b,
    const float* __restrict__ g2, const float* __restrict__ gateW,
    const float* __restrict__ gateb,
    float* __restrict__ xnbuf, float* __restrict__ h2buf,
    float* __restrict__ gw, int* __restrict__ tokslot,
    int* __restrict__ slottok, int* __restrict__ cnt) {
  const int tid = threadIdx.x;
  const int j = tid & 127, g = tid >> 7;
  const int lane = tid & 63;
  const int n0 = blockIdx.x * 4;
  const int b = n0 >> 9;

  __shared__ float4 bufA[128], bufB[128];
  __shared__ float4 part[3][128];
  __shared__ float4 gpart[256];
  __shared__ float4 rtmp[2];
  __shared__ float wvS[4][4]; __shared__ int wiS[4][4];
  __shared__ float zS[4][4];

  float xres[4];
  if (tid < 128) {
#pragma unroll
    for (int t = 0; t < 4; t++) xres[t] = x[(n0 + t) * Dd + j];
  }
  ((float*)&bufA[j])[g] = qbuf[(n0 + g) * Dd + j];
  __syncthreads();

  if (tid < 128) {
    int h = j >> 4, e = j & 15;
    const float* cpt = ctx + (b * NH + h) * 256;
    const float* kpt = ksum + (b * NH + h) * 16;
    float num[4] = {0, 0, 0, 0}, den[4] = {0, 0, 0, 0};
#pragma unroll
    for (int d = 0; d < 16; d++) {
      float cx = cpt[d * 16 + e], ks = kpt[d];
      float4 q4 = bufA[h * 16 + d];
      num[0] += q4.x * cx; num[1] += q4.y * cx; num[2] += q4.z * cx; num[3] += q4.w * cx;
      den[0] += q4.x * ks; den[1] += q4.y * ks; den[2] += q4.z * ks; den[3] += q4.w * ks;
    }
#pragma unroll
    for (int t = 0; t < 4; t++) ((float*)&bufB[j])[t] = num[t] / (den[t] + EPSF);
  }
  __syncthreads();

  {
    float a0 = 0, a1 = 0, a2 = 0, a3 = 0;
    const float* Wp = oR + (g * 32) * Dd + j;
#pragma unroll 16
    for (int i = 0; i < 32; i++) {
      float4 h4 = bufB[g * 32 + i];
      float w = Wp[i * Dd];
      a0 += h4.x * w; a1 += h4.y * w; a2 += h4.z * w; a3 += h4.w * w;
    }
    if (g) part[g - 1][j] = make_float4(a0, a1, a2, a3);
    __syncthreads();
    float tot[4];
    if (g == 0) {
      float4 p0 = part[0][j], p1 = part[1][j], p2 = part[2][j];
      float bb = bR[j];
      tot[0] = a0 + p0.x + p1.x + p2.x + bb; tot[1] = a1 + p0.y + p1.y + p2.y + bb;
      tot[2] = a2 + p0.z + p1.z + p2.z + bb; tot[3] = a3 + p0.w + p1.w + p2.w + bb;
      float v[4];
#pragma unroll
      for (int t = 0; t < 4; t++) v[t] = tot[t] * tot[t];
#pragma unroll
      for (int o = 32; o > 0; o >>= 1) {
#pragma unroll
        for (int t = 0; t < 4; t++) v[t] += __shfl_xor(v[t], o, 64);
      }
      if (lane == 0) rtmp[tid >> 6] = make_float4(v[0], v[1], v[2], v[3]);
    }
    __syncthreads();
    if (g == 0) {
      float scj = tqs[j];
#pragma unroll
      for (int t = 0; t < 4; t++) {
        float ss = ((const float*)&rtmp[0])[t] + ((const float*)&rtmp[1])[t];
        float mag = sqrtf(ss * (1.f / 128.f) + EPSF);
        float zc = fminf(fmaxf(tot[t], -mag), mag);
        ((float*)&bufA[j])[t] = zc * scj;
      }
    }
    __syncthreads();
  }

  {
    float a0 = 0, a1 = 0, a2 = 0, a3 = 0;
    const float* Wp = (g < 2 ? s1W : s2W) + ((g & 1) * 64) * Dd + j;
#pragma unroll 16
    for (int i = 0; i < 64; i++) {
      float4 h4 = bufA[(g & 1) * 64 + i];
      float w = Wp[i * Dd];
      a0 += h4.x * w; a1 += h4.y * w; a2 += h4.z * w; a3 += h4.w * w;
    }
    if (g) part[g - 1][j] = make_float4(a0, a1, a2, a3);
    __syncthreads();
    if (g == 0) {
      float b1 = s1b[j], b2 = s2b[j];
      float4 p0 = part[0][j], p1 = part[1][j], p2 = part[2][j];
      float gv[4], uv[4], xn[4], v[4];
      gv[0] = a0 + p0.x + b1; gv[1] = a1 + p0.y + b1;
      gv[2] = a2 + p0.z + b1; gv[3] = a3 + p0.w + b1;
      uv[0] = p1.x + p2.x + b2; uv[1] = p1.y + p2.y + b2;
      uv[2] = p1.z + p2.z + b2; uv[3] = p1.w + p2.w + b2;
      float g2j = g2[j];
#pragma unroll
      for (int t = 0; t < 4; t++) {
        xn[t] = xres[t] + gv[t] * sigm(gv[t]) * uv[t];
        xnbuf[(n0 + t) * Dd + j] = xn[t];
        ((float*)&bufB[j])[t] = g2j * xn[t];
        v[t] = xn[t] * xn[t];
      }
#pragma unroll
      for (int o = 32; o > 0; o >>= 1) {
#pragma unroll
        for (int t = 0; t < 4; t++) v[t] += __shfl_xor(v[t], o, 64);
      }
      if (lane == 0) rtmp[tid >> 6] = make_float4(v[0], v[1], v[2], v[3]);
    }
    __syncthreads();
  }

  float val[4];
  float r2[4];
  {
    int col = tid & 255, kh = tid >> 8;
    float a0 = 0, a1 = 0, a2 = 0, a3 = 0;
    const float* Wp = gateW + (kh * 64) * NE + col;
#pragma unroll 16
    for (int i = 0; i < 64; i++) {
      float4 h4 = bufB[kh * 64 + i];
      float w = Wp[i * NE];
      a0 += h4.x * w; a1 += h4.y * w; a2 += h4.z * w; a3 += h4.w * w;
    }
    if (kh) gpart[col] = make_float4(a0, a1, a2, a3);
    __syncthreads();
#pragma unroll
    for (int t = 0; t < 4; t++) {
      float ss = ((const float*)&rtmp[0])[t] + ((const float*)&rtmp[1])[t];
      r2[t] = rsqrtf(ss * (1.f / 128.f) + EPSF);
    }
    if (!kh) {
      float4 p = gpart[col];
      float bb = gateb[col];
      val[0] = (a0 + p.x) * r2[0] + bb; val[1] = (a1 + p.y) * r2[1] + bb;
      val[2] = (a2 + p.z) * r2[2] + bb; val[3] = (a3 + p.w) * r2[3] + bb;
    }
    if (tid < 128) {
#pragma unroll
      for (int t = 0; t < 4; t++)
        h2buf[(n0 + t) * Dd + j] = ((const float*)&bufB[j])[t] * r2[t];
    }
  }
  __syncthreads();

  float m1[4]; int i1[4];
  {
    if (tid < 256) {
      float bv[4]; int bi[4];
#pragma unroll
      for (int t = 0; t < 4; t++) { bv[t] = val[t]; bi[t] = tid; }
#pragma unroll
      for (int o = 32; o > 0; o >>= 1) {
#pragma unroll
        for (int t = 0; t < 4; t++) {
          float wv = __shfl_xor(bv[t], o, 64);
          int wi = __shfl_xor(bi[t], o, 64);
          if (wv > bv[t] || (wv == bv[t] && wi < bi[t])) { bv[t] = wv; bi[t] = wi; }
        }
      }
      if (lane == 0) {
#pragma unroll
        for (int t = 0; t < 4; t++) { wvS[tid >> 6][t] = bv[t]; wiS[tid >> 6][t] = bi[t]; }
      }
    }
    __syncthreads();
    if (tid < 256) {
#pragma unroll
      for (int t = 0; t < 4; t++) {
        m1[t] = wvS[0][t]; i1[t] = wiS[0][t];
#pragma unroll
        for (int w = 1; w < 4; w++) {
          float cv = wvS[w][t]; int ci = wiS[w][t];
          if (cv > m1[t] || (cv == m1[t] && ci < i1[t])) { m1[t] = cv; i1[t] = ci; }
        }
      }
    }
    __syncthreads();
  }
  float m2[4]; int i2[4];
  {
    if (tid < 256) {
      float bv[4]; int bi[4];
#pragma unroll
      for (int t = 0; t < 4; t++) {
        bv[t] = (tid == i1[t]) ? -INFINITY : val[t];
        bi[t] = tid;
      }
#pragma unroll
      for (int o = 32; o > 0; o >>= 1) {
#pragma unroll
        for (int t = 0; t < 4; t++) {
          float wv = __shfl_xor(bv[t], o, 64);
          int wi = __shfl_xor(bi[t], o, 64);
          if (wv > bv[t] || (wv == bv[t] && wi < bi[t])) { bv[t] = wv; bi[t] = wi; }
        }
      }
      if (lane == 0) {
#pragma unroll
        for (int t = 0; t < 4; t++) { wvS[tid >> 6][t] = bv[t]; wiS[tid >> 6][t] = bi[t]; }
      }
    }
    __syncthreads();
    if (tid < 256) {
#pragma unroll
      for (int t = 0; t < 4; t++) {
        m2[t] = wvS[0][t]; i2[t] = wiS[0][t];
#pragma unroll
        for (int w = 1; w < 4; w++) {
          float cv = wvS[w][t]; int ci = wiS[w][t];
          if (cv > m2[t] || (cv == m2[t] && ci < i2[t])) { m2[t] = cv; i2[t] = ci; }
        }
      }
    }
    __syncthreads();
  }
  {
    if (tid < 256) {
      float v[4];
#pragma unroll
      for (int t = 0; t < 4; t++) v[t] = expf(val[t] - m1[t]);
#pragma unroll
      for (int o = 32; o > 0; o >>= 1) {
#pragma unroll
        for (int t = 0; t < 4; t++) v[t] += __shfl_xor(v[t], o, 64);
      }
      if (lane == 0) {
#pragma unroll
        for (int t = 0; t < 4; t++) zS[tid >> 6][t] = v[t];
      }
    }
    __syncthreads();
  }
  if (tid < 4) {
    int t = tid, tok = n0 + t;
    float Z = zS[0][t] + zS[1][t] + zS[2][t] + zS[3][t];
    float p1 = 1.f / Z;
    float p2 = expf(m2[t] - m1[t]) / Z;
    float s = p1 + p2 + EPSF;
    int e1 = i1[t], e2 = i2[t];
    int s1 = atomicAdd(&cnt[e1], 1); if (s1 > SLOTS - 1) s1 = SLOTS - 1;
    int s2 = atomicAdd(&cnt[e2], 1); if (s2 > SLOTS - 1) s2 = SLOTS - 1;
    int sl1 = e1 * SLOTS + s1, sl2 = e2 * SLOTS + s2;
    slottok[sl1] = tok; slottok[sl2] = tok;
    tokslot[tok * 2] = sl1; tokslot[tok * 2 + 1] = sl2;
    gw[tok * 2] = p1 / s; gw[tok * 2 + 1] = p2 / s;
  }
}

__global__ __launch_bounds__(512) void k_exp_fb(const float* __restrict__ h2buf,
                                                const int* __restrict__ slottok,
                                                const int* __restrict__ cnt,
                                                const float* __restrict__ expW,
                                                float* __restrict__ ybuf) {
  const int e = blockIdx.x >> 1, sub = blockIdx.x & 1;
  int n = cnt[e]; if (n > SLOTS) n = SLOTS;
  const int base = e * SLOTS;
  const int tid = threadIdx.x;
  const int j = tid & 127, g = tid >> 7;
  __shared__ __align__(16) float hT[128 * 20];
  const float* Wp = expW + (size_t)e * Dd * Dd + j;
  for (int t0 = sub * 16; t0 < n; t0 += 32) {
    int m = n - t0; if (m > 16) m = 16;
    __syncthreads();
    for (int tt = g; tt < m; tt += 4) {
      int tok = slottok[base + t0 + tt];
      hT[j * 20 + tt] = h2buf[tok * Dd + j];
    }
    __syncthreads();
    float acc[4] = {0, 0, 0, 0};
#pragma unroll 8
    for (int i = 0; i < 128; i++) {
      float w = Wp[i * Dd];
      float4 h4 = *(const float4*)&hT[i * 20 + g * 4];
      acc[0] += h4.x * w; acc[1] += h4.y * w; acc[2] += h4.z * w; acc[3] += h4.w * w;
    }
#pragma unroll
    for (int k = 0; k < 4; k++) {
      int tt = g * 4 + k;
      if (tt < m) ybuf[(size_t)(base + t0 + tt) * Dd + j] = acc[k];
    }
  }
}

__global__ __launch_bounds__(512) void k_post_fb(
    const float* __restrict__ xnbuf, const float* __restrict__ ybuf,
    const int* __restrict__ tokslot, const float* __restrict__ gw,
    const float* __restrict__ m1W, const float* __restrict__ m1b,
    const float* __restrict__ m2W, const float* __restrict__ m2b,
    float* __restrict__ out) {
  const int tid = threadIdx.x;
  const int j = tid & 127, g = tid >> 7;
  const int lane = tid & 63;
  const int n0 = blockIdx.x * 4;

  __shared__ float4 y1T[128], y2T[128], inT[128], sT[128];
  __shared__ float4 part[3][128];
  __shared__ float4 rtmp[2];
  __shared__ int sSlot[4][2];
  __shared__ float sWt[4][2];

  if (tid < 4) {
    sSlot[tid][0] = tokslot[(n0 + tid) * 2];
    sSlot[tid][1] = tokslot[(n0 + tid) * 2 + 1];
    sWt[tid][0] = gw[(n0 + tid) * 2];
    sWt[tid][1] = gw[(n0 + tid) * 2 + 1];
  }
  __syncthreads();

  {
    float y1 = ybuf[(size_t)sSlot[g][0] * Dd + j];
    float y2 = ybuf[(size_t)sSlot[g][1] * Dd + j];
    ((float*)&y1T[j])[g] = y1;
    ((float*)&y2T[j])[g] = y2;
    ((float*)&inT[j])[g] = sWt[g][0] * y1 + sWt[g][1] * y2;
  }
  __syncthreads();

  {
    float a0 = 0, a1 = 0, a2 = 0, a3 = 0;
    const float* Wp = (g < 2 ? m1W : m2W) + ((g & 1) * 64) * Dd + j;
#pragma unroll 16
    for (int i = 0; i < 64; i++) {
      float4 h4 = inT[(g & 1) * 64 + i];
      float w = Wp[i * Dd];
      a0 += h4.x * w; a1 += h4.y * w; a2 += h4.z * w; a3 += h4.w * w;
    }
    if (g) part[g - 1][j] = make_float4(a0, a1, a2, a3);
    __syncthreads();
    if (g == 0) {
      float b1 = m1b[j], b2 = m2b[j];
      float4 p0 = part[0][j], p1 = part[1][j], p2 = part[2][j];
      float gv[4], uv[4];
      gv[0] = a0 + p0.x + b1; gv[1] = a1 + p0.y + b1;
      gv[2] = a2 + p0.z + b1; gv[3] = a3 + p0.w + b1;
      uv[0] = p1.x + p2.x + b2; uv[1] = p1.y + p2.y + b2;
      uv[2] = p1.z + p2.z + b2; uv[3] = p1.w + p2.w + b2;
#pragma unroll
      for (int t = 0; t < 4; t++) {
        float sv = gv[t] * sigm(gv[t]) * uv[t];
        ((float*)&sT[j])[t] = sv;
        out[(n0 + t) * Dd + j] = xnbuf[(n0 + t) * Dd + j] + sv;
      }
    }
    __syncthreads();
  }

  if (tid < 128) {
    float v[4];
#pragma unroll
    for (int t = 0; t < 4; t++) {
      float sv = ((const float*)&sT[j])[t];
      float d1 = ((const float*)&y1T[j])[t] - sv;
      float d2 = ((const float*)&y2T[j])[t] - sv;
      v[t] = sWt[t][0] * d1 * d1 + sWt[t][1] * d2 * d2;
    }
#pragma unroll
    for (int o = 32; o > 0; o >>= 1) {
#pragma unroll
      for (int t = 0; t < 4; t++) v[t] += __shfl_xor(v[t], o, 64);
    }
    if (lane == 0) rtmp[tid >> 6] = make_float4(v[0], v[1], v[2], v[3]);
  }
  __syncthreads();
  if (tid < 4) {
    float s = ((const float*)&rtmp[0])[tid] + ((const float*)&rtmp[1])[tid];
    out[NTOK * Dd + n0 + tid] = expf(-s * (1.f / 128.f));
  }
}

// ============================================================================
extern "C" void kernel_launch(void* const* d_in, const int* in_sizes, int n_in,
                              void* d_out, int out_size, void* d_ws, size_t ws_size,
                              hipStream_t stream) {
  const float* x   = (const float*)d_in[0];
  const float* g1  = (const float*)d_in[1];
  const float* qW  = (const float*)d_in[2];
  const float* qb  = (const float*)d_in[3];
  const float* kdW = (const float*)d_in[4];
  const float* kdb = (const float*)d_in[5];
  const float* kuW = (const float*)d_in[6];
  const float* kub = (const float*)d_in[7];
  const float* oW  = (const float*)d_in[8];
  const float* ob  = (const float*)d_in[9];
  const float* rot = (const float*)d_in[10];
  const float* tqs = (const float*)d_in[11];
  const float* s1W = (const float*)d_in[12];
  const float* s1b = (const float*)d_in[13];
  const float* s2W = (const float*)d_in[14];
  const float* s2b = (const float*)d_in[15];
  const float* g2  = (const float*)d_in[16];
  const float* gW  = (const float*)d_in[17];
  const float* gb  = (const float*)d_in[18];
  const float* eW  = (const float*)d_in[19];
  const float* m1W = (const float*)d_in[20];
  const float* m1b = (const float*)d_in[21];
  const float* m2W = (const float*)d_in[22];
  const float* m2b = (const float*)d_in[23];
  float* out = (float*)d_out;
  float* ws  = (float*)d_ws;

  float* ctx     = ws;                    // 8192
  float* ksum    = ws + 8192;             // 512
  float* oR      = ws + 8704;             // 16384
  float* bR      = ws + 25088;            // 128
  float* qbuf    = ws + 25216;            // 262144
  float* kvbuf   = ws + 287360;           // 524288
  float* h2buf   = ws + 811648;           // 262144
  float* ybuf    = ws + 1073792;          // 8388608
  int*   cnt     = (int*)(ws + 9462400);  // 256
  int*   slottok = (int*)(ws + 9462656);  // 65536
  int*   flags   = (int*)(ws + 9528192);  // 261
  float* xnbuf   = ws + 9528576;          // 262144  (fallback only)
  float* gw      = ws + 9790720;          // 4096    (fallback only)
  int*   tokslot = (int*)(ws + 9794816);  // 4096    (fallback only)

  k_pre<<<NTOK / 4, 512, 0, stream>>>(x, g1, qW, qb, kdW, kdb, kuW, kub,
                                      oW, ob, rot, qbuf, kvbuf, ctx, ksum,
                                      cnt, flags, oR, bR);

  RParams p;
  p.x = x; p.qbuf = qbuf; p.kvbuf = kvbuf; p.oR = oR; p.bR = bR; p.tqs = tqs;
  p.s1W = s1W; p.s1b = s1b; p.s2W = s2W; p.s2b = s2b; p.g2 = g2;
  p.gateW = gW; p.gateb = gb; p.expW = eW;
  p.m1W = m1W; p.m1b = m1b; p.m2W = m2W; p.m2b = m2b;
  p.ctx = ctx; p.ksum = ksum; p.h2buf = h2buf; p.ybuf = ybuf; p.out = out;
  p.cnt = cnt; p.slottok = slottok; p.flags = flags;

  void* args[] = {(void*)&p};
  hipError_t err = hipErrorUnknown;
  int nb = 0;
  if (hipOccupancyMaxActiveBlocksPerMultiprocessor(
          &nb, reinterpret_cast<const void*>(&k_rest), 512, 0) == hipSuccess &&
      nb >= 2) {
    err = hipLaunchCooperativeKernel((void*)k_rest, dim3(NTOK / 4), dim3(512),
                                     args, 0u, stream);
  }
  if (err == hipSuccess) return;

  // ---- fallback: proven R0-style chain -------------------------------------
  k_ctx_fb<<<256, 256, 0, stream>>>(kvbuf, ctx, ksum);
  k_mid_fb<<<NTOK / 4, 512, 0, stream>>>(x, qbuf, ctx, ksum, oR, bR, tqs,
                                         s1W, s1b, s2W, s2b, g2, gW, gb,
                                         xnbuf, h2buf, gw, tokslot, slottok, cnt);
  k_exp_fb<<<NE * 2, 512, 0, stream>>>(h2buf, slottok, cnt, eW, ybuf);
  k_post_fb<<<NTOK / 4, 512, 0, stream>>>(xnbuf, ybuf, tokslot, gw,
                                          m1W, m1b, m2W, m2b, out);
}